// Round 1
// baseline (209.083 us; speedup 1.0000x reference)
//
#include <hip/hip_runtime.h>
#include <hip/hip_bf16.h>
#include <cmath>

#define N_NODES 50000
#define N_EDGES 800000
#define D_IN 256
#define D_HID 128
#define D_ENC 64
#define NBUK 128         // dest buckets, bucket = c >> 9 (98 used)
#define BSH 9
#define BMSK 511
#define BCAP 16384       // fixed bucket capacity (expected ~8.2K, huge margin)
#define PB_EPT 16        // edges per thread in part_k (4096/block)

typedef short short8 __attribute__((ext_vector_type(8)));
typedef float floatx4 __attribute__((ext_vector_type(4)));
typedef float floatx8 __attribute__((ext_vector_type(8)));
typedef unsigned short ushort8v __attribute__((ext_vector_type(8)));

static __device__ __forceinline__ unsigned short f2bf(float f) {
    unsigned int u = __float_as_uint(f);
    unsigned int r = (u + 0x7FFFu + ((u >> 16) & 1u)) >> 16;   // RNE
    return (unsigned short)r;
}
static __device__ __forceinline__ float bf2f(unsigned short u) {
    return __uint_as_float(((unsigned int)u) << 16);
}
static __device__ __forceinline__ floatx8 bf2f8(ushort8v u) {
    floatx8 f;
#pragma unroll
    for (int j = 0; j < 8; ++j) f[j] = bf2f(u[j]);
    return f;
}

// ---------------- W pre-swizzle into B-fragment layout (bf16) ----------------
static __device__ __forceinline__ void wswz(const float* __restrict__ W,
                                            unsigned short* __restrict__ Wsw,
                                            int t, int K, int N) {
    int KS = K / 32;
    int lane = t & 63;
    int ks   = (t >> 6) % KS;
    int ct   = (t >> 6) / KS;
    int m = lane & 15, quad = lane >> 4;
    int kbase = ks * 32 + quad * 8;
    int col   = ct * 16 + m;
#pragma unroll
    for (int j = 0; j < 8; ++j)
        Wsw[t * 8 + j] = f2bf(W[(size_t)(kbase + j) * N + col]);
}

// ---------------- radix partition: block-local counting sort + coalesced flush ----------------
// brecs rec = (src << 16) | dst. Bucket b occupies [b*BCAP, b*BCAP + count).
__global__ __launch_bounds__(256) void part_k(const int* __restrict__ rows,
                                              const int* __restrict__ cols,
                                              int* __restrict__ bcur,
                                              unsigned int* __restrict__ brecs,
                                              const float* __restrict__ W1,
                                              const float* __restrict__ W2,
                                              unsigned short* __restrict__ Wsw1,
                                              unsigned short* __restrict__ Wsw2) {
    __shared__ unsigned int recs[256 * PB_EPT];   // 16 KB, bucket-grouped
    __shared__ int h[NBUK], ex[NBUK], gbase[NBUK];
    int tid = threadIdx.x;
    // fused weight swizzle on the first 20 blocks
    int t = blockIdx.x * 256 + tid;
    if (t < 4096) wswz(W1, Wsw1, t, D_IN, D_HID);
    else if (t < 5120) wswz(W2, Wsw2, t - 4096, D_HID, D_ENC);

    if (tid < NBUK) h[tid] = 0;
    __syncthreads();
    int e0 = blockIdx.x * (256 * PB_EPT);
    unsigned int myrec[PB_EPT];
    int myb[PB_EPT];
#pragma unroll
    for (int j = 0; j < PB_EPT; ++j) {
        int e = e0 + j * 256 + tid;
        if (e < N_EDGES) {
            int s = __builtin_nontemporal_load(&rows[e]);   // single-touch stream
            int d = __builtin_nontemporal_load(&cols[e]);
            myrec[j] = ((unsigned int)s << 16) | (unsigned int)d;
            myb[j] = d >> BSH;
            atomicAdd(&h[myb[j]], 1);
        } else myb[j] = -1;
    }
    __syncthreads();
    if (tid < NBUK) {
        int c = h[tid];
        gbase[tid] = tid * BCAP + (c ? atomicAdd(&bcur[tid], c) : 0);
        ex[tid] = c;
    }
    __syncthreads();
    for (int off = 1; off < NBUK; off <<= 1) {
        int v = 0;
        if (tid < NBUK && tid >= off) v = ex[tid - off];
        __syncthreads();
        if (tid < NBUK) ex[tid] += v;
        __syncthreads();
    }
    if (tid < NBUK) { ex[tid] -= h[tid]; h[tid] = 0; }
    __syncthreads();
#pragma unroll
    for (int j = 0; j < PB_EPT; ++j) {
        if (myb[j] >= 0) {
            int p = ex[myb[j]] + atomicAdd(&h[myb[j]], 1);
            recs[p] = myrec[j];
        }
    }
    __syncthreads();
    int w = tid >> 6, lane = tid & 63;
    for (int b = w; b < NBUK; b += 4) {
        int start = ex[b], cnt = h[b], gb = gbase[b];
        int lim = (b + 1) * BCAP;
        for (int i = lane; i < cnt; i += 64) {
            int gp = gb + i;
            if (gp < lim) brecs[gp] = recs[start + i];
        }
    }
}

// ---------------- per-bucket CSR: count+scan+dinv+fill, all in LDS ----------------
__global__ __launch_bounds__(512) void bucket_csr_k(const unsigned int* __restrict__ brecs,
                                                    const int* __restrict__ bcur,
                                                    int* __restrict__ rowptr,
                                                    int* __restrict__ rowcnt,
                                                    unsigned short* __restrict__ srcs,
                                                    float* __restrict__ dinv) {
    __shared__ int s[512];
    __shared__ int cur[512];
    int b = blockIdx.x;
    int cb = bcur[b]; if (cb > BCAP) cb = BCAP;
    int ebeg = b * BCAP, eend = ebeg + cb;
    int tid = threadIdx.x;
    s[tid] = 0;
    __syncthreads();
    for (int e = ebeg + tid; e < eend; e += 512)
        atomicAdd(&s[brecs[e] & BMSK], 1);
    __syncthreads();
    int v = s[tid];
    for (int off = 1; off < 512; off <<= 1) {
        int t = (tid >= off) ? s[tid - off] : 0;
        __syncthreads();
        s[tid] += t;
        __syncthreads();
    }
    int excl = s[tid] - v;
    cur[tid] = excl;
    int node = (b << BSH) + tid;
    if (node < N_NODES) {
        rowptr[node] = ebeg + excl;
        rowcnt[node] = v;
        dinv[node] = rsqrtf((float)(v + 1));   // +1 self-loop
    }
    __syncthreads();
    for (int e = ebeg + tid; e < eend; e += 512) {
        unsigned int rec = brecs[e];
        int p = atomicAdd(&cur[rec & BMSK], 1);
        srcs[ebeg + p] = (unsigned short)(rec >> 16);
    }
}

// ---------------- MFMA GEMM: H[r,:] = bf16(dinv[r] * (X[r,:] @ W)) ----------------
template<int K, int N, bool IN_BF16>
__global__ __launch_bounds__(256) void gemm_mfma_k(const void* __restrict__ Xv,
                                                   const unsigned short* __restrict__ Wsw,
                                                   const float* __restrict__ dinv,
                                                   unsigned short* __restrict__ H, int n) {
    constexpr int KS = K / 32, CT = N / 16, KP = K + 8;
    __shared__ unsigned short As[64 * KP];
    int row0 = blockIdx.x * 64;
    if (IN_BF16) {
        const ushort8v* X8 = (const ushort8v*)Xv;
        constexpr int NF8 = 64 * (K / 8);
        for (int idx = threadIdx.x; idx < NF8; idx += 256) {
            int r = idx / (K / 8), c8 = idx % (K / 8);
            int gr = row0 + r;
            ushort8v v = (gr < n) ? X8[(size_t)gr * (K / 8) + c8] : (ushort8v)0;
            *(ushort8v*)&As[r * KP + c8 * 8] = v;
        }
    } else {
        const floatx4* X4 = (const floatx4*)Xv;
        constexpr int NF4 = 64 * (K / 4);
        for (int idx = threadIdx.x; idx < NF4; idx += 256) {
            int r = idx / (K / 4), c4 = idx % (K / 4);
            int gr = row0 + r;
            floatx4 v = (gr < n) ? __builtin_nontemporal_load(&X4[(size_t)gr * (K / 4) + c4])
                                 : (floatx4){0, 0, 0, 0};                    // X is single-touch
            __hip_bfloat162 p0 = __float22bfloat162_rn(float2{v[0], v[1]});  // packed RNE cvt
            __hip_bfloat162 p1 = __float22bfloat162_rn(float2{v[2], v[3]});
            uint2 u; u.x = *(unsigned int*)&p0; u.y = *(unsigned int*)&p1;
            *(uint2*)&As[r * KP + c4 * 4] = u;
        }
    }
    __syncthreads();

    int w    = threadIdx.x >> 6;
    int lane = threadIdx.x & 63;
    int m    = lane & 15;
    int quad = lane >> 4;

    floatx4 acc[CT];
#pragma unroll
    for (int ct = 0; ct < CT; ++ct)
#pragma unroll
        for (int i = 0; i < 4; ++i) acc[ct][i] = 0.0f;

#pragma unroll
    for (int ks = 0; ks < KS; ++ks) {
        short8 af = *(const short8*)&As[(w * 16 + m) * KP + ks * 32 + quad * 8];
#pragma unroll
        for (int ct = 0; ct < CT; ++ct) {
            short8 bf = *(const short8*)&Wsw[(size_t)((ct * KS + ks) * 64 + lane) * 8];
            acc[ct] = __builtin_amdgcn_mfma_f32_16x16x32_bf16(af, bf, acc[ct], 0, 0, 0);
        }
    }

    int rbase = row0 + w * 16 + quad * 4;
    float dv[4];
#pragma unroll
    for (int reg = 0; reg < 4; ++reg) {
        int r = rbase + reg;
        dv[reg] = (r < n) ? dinv[r] : 0.0f;
    }
#pragma unroll
    for (int ct = 0; ct < CT; ++ct)
#pragma unroll
        for (int reg = 0; reg < 4; ++reg) {
            int r = rbase + reg;
            if (r < n) H[(size_t)r * N + ct * 16 + m] = f2bf(acc[ct][reg] * dv[reg]);
        }
}

// ---------------- fused gather1 + gemm2: h2 = bf16(dinv*(relu-gathered a1 @ W2)) ----------------
// Block = 512 (8 waves), 16 nodes/block. Each node gets 32 lanes: 2 edge-halves x
// 16 channel-lanes, each half walks half the edge list with x4 chains, combined
// with one shfl_xor(16) per channel. Halves the serial gather chain AND the
// barrier imbalance (max-degree stretch) vs 16-lane/node.
__global__ __launch_bounds__(512) void g1g2_k(const ushort8v* __restrict__ hs,
                                              const int* __restrict__ rowptr,
                                              const int* __restrict__ rowcnt,
                                              const unsigned short* __restrict__ srcs,
                                              const float* __restrict__ dinv,
                                              const float4* __restrict__ b1_4,
                                              const unsigned short* __restrict__ Wsw2,
                                              unsigned short* __restrict__ h2) {
    constexpr int KP = D_HID + 8;   // 136
    __shared__ unsigned short As[16 * KP];
    int tid = threadIdx.x;
    int nodeb = blockIdx.x * 16;    // 50000 = 3125*16 exactly
    int ln = tid >> 5;              // local node 0..15
    int hh = (tid >> 4) & 1;        // edge-half 0/1
    int d8 = tid & 15;              // channel slice
    int node = nodeb + ln;
    int beg = rowptr[node];
    int cnt = rowcnt[node];
    int half0 = (cnt + 1) >> 1;
    int hb = beg + (hh ? half0 : 0);
    int he = hh ? (beg + cnt) : (beg + half0);
    floatx8 a0 = {0,0,0,0,0,0,0,0}, a1 = a0, a2 = a0, a3 = a0;
    int i = hb;
    for (; i + 4 <= he; i += 4) {
        int s0 = srcs[i], s1 = srcs[i + 1], s2 = srcs[i + 2], s3 = srcs[i + 3];
        a0 += bf2f8(hs[(size_t)s0 * 16 + d8]);
        a1 += bf2f8(hs[(size_t)s1 * 16 + d8]);
        a2 += bf2f8(hs[(size_t)s2 * 16 + d8]);
        a3 += bf2f8(hs[(size_t)s3 * 16 + d8]);
    }
    for (; i < he; ++i)
        a0 += bf2f8(hs[(size_t)srcs[i] * 16 + d8]);
    floatx8 acc = a0 + a1 + a2 + a3;
    if (!hh) acc += bf2f8(hs[(size_t)node * 16 + d8]);   // + self-loop (once)
#pragma unroll
    for (int j = 0; j < 8; ++j)
        acc[j] += __shfl_xor(acc[j], 16, 64);            // combine halves
    if (!(tid & 16)) {
        float di = dinv[node];
        float4 bA = b1_4[d8 * 2], bB = b1_4[d8 * 2 + 1];
        ushort8v r;
        r[0] = f2bf(fmaxf(di * acc[0] + bA.x, 0.0f));
        r[1] = f2bf(fmaxf(di * acc[1] + bA.y, 0.0f));
        r[2] = f2bf(fmaxf(di * acc[2] + bA.z, 0.0f));
        r[3] = f2bf(fmaxf(di * acc[3] + bA.w, 0.0f));
        r[4] = f2bf(fmaxf(di * acc[4] + bB.x, 0.0f));
        r[5] = f2bf(fmaxf(di * acc[5] + bB.y, 0.0f));
        r[6] = f2bf(fmaxf(di * acc[6] + bB.z, 0.0f));
        r[7] = f2bf(fmaxf(di * acc[7] + bB.w, 0.0f));
        *(ushort8v*)&As[ln * KP + d8 * 8] = r;
    }
    __syncthreads();

    // phase 2: one 16-row M-tile; waves 0..3 handle col-tile w (16 cols), KS=4
    constexpr int KS = D_HID / 32;
    int w = tid >> 6;
    if (w < 4) {
        int lane = tid & 63;
        int m = lane & 15, quad = lane >> 4;
        floatx4 acc2 = {0, 0, 0, 0};
#pragma unroll
        for (int ks = 0; ks < KS; ++ks) {
            short8 af = *(const short8*)&As[m * KP + ks * 32 + quad * 8];
            short8 bf = *(const short8*)&Wsw2[(size_t)((w * KS + ks) * 64 + lane) * 8];
            acc2 = __builtin_amdgcn_mfma_f32_16x16x32_bf16(af, bf, acc2, 0, 0, 0);
        }
#pragma unroll
        for (int reg = 0; reg < 4; ++reg) {
            int nn = nodeb + quad * 4 + reg;
            h2[(size_t)nn * D_ENC + w * 16 + m] = f2bf(acc2[reg] * dinv[nn]);
        }
    }
}

// ---------------- gather layer 2 + FC + sigmoid ----------------
// 16 lanes per node: 2 edge-halves x 8 channel-lanes (ushort8 over 64 ch),
// 16 nodes/block, x4 chains per half, shfl_xor(8) combine.
__global__ __launch_bounds__(256) void gather2_k(const ushort8v* __restrict__ hs, const int* __restrict__ rowptr,
                          const int* __restrict__ rowcnt, const unsigned short* __restrict__ srcs,
                          const float* __restrict__ dinv,
                          const float4* __restrict__ b4, const float4* __restrict__ Wfc4,
                          const float* __restrict__ bfc, float* __restrict__ out) {
    int tid = threadIdx.x;
    int node = blockIdx.x * 16 + (tid >> 4);   // grid = 3125, 50000 exact
    int hh = (tid >> 3) & 1;
    int d8 = tid & 7;
    int beg = rowptr[node];
    int cnt = rowcnt[node];
    int half0 = (cnt + 1) >> 1;
    int hb = beg + (hh ? half0 : 0);
    int he = hh ? (beg + cnt) : (beg + half0);
    floatx8 a0 = {0,0,0,0,0,0,0,0}, a1 = a0, a2 = a0, a3 = a0;
    int i = hb;
    for (; i + 4 <= he; i += 4) {
        int s0 = srcs[i], s1 = srcs[i + 1], s2 = srcs[i + 2], s3 = srcs[i + 3];
        a0 += bf2f8(hs[(size_t)s0 * 8 + d8]);
        a1 += bf2f8(hs[(size_t)s1 * 8 + d8]);
        a2 += bf2f8(hs[(size_t)s2 * 8 + d8]);
        a3 += bf2f8(hs[(size_t)s3 * 8 + d8]);
    }
    for (; i < he; ++i)
        a0 += bf2f8(hs[(size_t)srcs[i] * 8 + d8]);
    floatx8 acc = a0 + a1 + a2 + a3;
    if (!hh) acc += bf2f8(hs[(size_t)node * 8 + d8]);    // + self-loop (once)
#pragma unroll
    for (int j = 0; j < 8; ++j)
        acc[j] += __shfl_xor(acc[j], 8, 64);             // combine halves
    if (tid & 8) return;                                 // half 1 done
    float di = dinv[node];
    float4 bA = b4[d8 * 2], bB = b4[d8 * 2 + 1];
    float4 wA = Wfc4[d8 * 2], wB = Wfc4[d8 * 2 + 1];
    float p = (di * acc[0] + bA.x) * wA.x + (di * acc[1] + bA.y) * wA.y
            + (di * acc[2] + bA.z) * wA.z + (di * acc[3] + bA.w) * wA.w
            + (di * acc[4] + bB.x) * wB.x + (di * acc[5] + bB.y) * wB.y
            + (di * acc[6] + bB.z) * wB.z + (di * acc[7] + bB.w) * wB.w;
#pragma unroll
    for (int off = 4; off; off >>= 1) p += __shfl_down(p, off, 8);
    if (d8 == 0) out[node] = 1.0f / (1.0f + expf(-(p + bfc[0])));
}

extern "C" void kernel_launch(void* const* d_in, const int* in_sizes, int n_in,
                              void* d_out, int out_size, void* d_ws, size_t ws_size,
                              hipStream_t stream) {
    const float* x   = (const float*)d_in[0];
    const int*   ei  = (const int*)d_in[1];     // [2, E] int32
    const float* W1  = (const float*)d_in[2];
    const float* b1  = (const float*)d_in[3];
    const float* W2  = (const float*)d_in[4];
    const float* b2  = (const float*)d_in[5];
    const float* Wfc = (const float*)d_in[6];
    const float* bfc = (const float*)d_in[7];
    float* out = (float*)d_out;

    const int* rows = ei;             // sources
    const int* cols = ei + N_EDGES;   // targets

    // workspace layout (16B alignment kept for vector types)
    float* ws     = (float*)d_ws;
    float* dinv   = ws;                                   // 50048
    int*   rowptr = (int*)(ws + 50048);                   // 50048
    int*   rowcnt = rowptr + 50048;                       // 50048
    int*   bcur   = rowcnt + 50048;                       // 128
    unsigned int* brecs = (unsigned int*)(bcur + 128);    // NBUK*BCAP u32 (8MB)
    unsigned short* srcs = (unsigned short*)(brecs + NBUK * BCAP);  // NBUK*BCAP u16 (4MB)
    unsigned short* h1 = srcs + (size_t)NBUK * BCAP;               // 6.4M us
    unsigned short* h2 = h1 + (size_t)N_NODES * D_HID;             // 3.2M us
    unsigned short* Wsw1 = h2 + (size_t)N_NODES * D_ENC;           // 32768 us
    unsigned short* Wsw2 = Wsw1 + (size_t)D_IN * D_HID;            // 8192 us

    // ---- CSR build: fixed-capacity buckets; bcur = per-bucket counts ----
    hipMemsetAsync(bcur, 0, NBUK * sizeof(int), stream);
    part_k<<<(N_EDGES + 256 * PB_EPT - 1) / (256 * PB_EPT), 256, 0, stream>>>(
        rows, cols, bcur, brecs, W1, W2, Wsw1, Wsw2);
    bucket_csr_k<<<(N_NODES + 511) / 512, 512, 0, stream>>>(brecs, bcur, rowptr, rowcnt, srcs, dinv);

    // ---- layer 1 GEMM ----
    gemm_mfma_k<D_IN, D_HID, false><<<(N_NODES + 63) / 64, 256, 0, stream>>>(x, Wsw1, dinv, h1, N_NODES);

    // ---- fused gather1 + gemm2 ----
    g1g2_k<<<N_NODES / 16, 512, 0, stream>>>((const ushort8v*)h1, rowptr, rowcnt, srcs, dinv,
                                             (const float4*)b1, Wsw2, h2);

    // ---- gather2 + FC + sigmoid ----
    gather2_k<<<N_NODES / 16, 256, 0, stream>>>((const ushort8v*)h2, rowptr, rowcnt, srcs, dinv,
                                                (const float4*)b2, (const float4*)Wfc,
                                                bfc, out);
}

// Round 2
// 193.910 us; speedup vs baseline: 1.0782x; 1.0782x over previous
//
#include <hip/hip_runtime.h>
#include <hip/hip_bf16.h>
#include <cmath>

#define N_NODES 50000
#define N_EDGES 800000
#define D_IN 256
#define D_HID 128
#define D_ENC 64
#define NBUK 128         // dest buckets, bucket = c >> 9 (98 used)
#define BSH 9
#define BMSK 511
#define BCAP 16384       // fixed bucket capacity (expected ~8.2K, huge margin)
#define PB_EPT 16        // edges per thread in part_k (4096/block)

typedef short short8 __attribute__((ext_vector_type(8)));
typedef float floatx4 __attribute__((ext_vector_type(4)));
typedef float floatx8 __attribute__((ext_vector_type(8)));
typedef unsigned short ushort8v __attribute__((ext_vector_type(8)));

static __device__ __forceinline__ unsigned short f2bf(float f) {
    unsigned int u = __float_as_uint(f);
    unsigned int r = (u + 0x7FFFu + ((u >> 16) & 1u)) >> 16;   // RNE
    return (unsigned short)r;
}
static __device__ __forceinline__ float bf2f(unsigned short u) {
    return __uint_as_float(((unsigned int)u) << 16);
}
static __device__ __forceinline__ floatx8 bf2f8(ushort8v u) {
    floatx8 f;
#pragma unroll
    for (int j = 0; j < 8; ++j) f[j] = bf2f(u[j]);
    return f;
}

// ---------------- W pre-swizzle into B-fragment layout (bf16) ----------------
static __device__ __forceinline__ void wswz(const float* __restrict__ W,
                                            unsigned short* __restrict__ Wsw,
                                            int t, int K, int N) {
    int KS = K / 32;
    int lane = t & 63;
    int ks   = (t >> 6) % KS;
    int ct   = (t >> 6) / KS;
    int m = lane & 15, quad = lane >> 4;
    int kbase = ks * 32 + quad * 8;
    int col   = ct * 16 + m;
#pragma unroll
    for (int j = 0; j < 8; ++j)
        Wsw[t * 8 + j] = f2bf(W[(size_t)(kbase + j) * N + col]);
}

// ---------------- radix partition: block-local counting sort + coalesced flush ----------------
// brecs rec = (src << 16) | dst. Bucket b occupies [b*BCAP, b*BCAP + count).
__global__ __launch_bounds__(256) void part_k(const int* __restrict__ rows,
                                              const int* __restrict__ cols,
                                              int* __restrict__ bcur,
                                              unsigned int* __restrict__ brecs,
                                              const float* __restrict__ W1,
                                              const float* __restrict__ W2,
                                              unsigned short* __restrict__ Wsw1,
                                              unsigned short* __restrict__ Wsw2) {
    __shared__ unsigned int recs[256 * PB_EPT];   // 16 KB, bucket-grouped
    __shared__ int h[NBUK], ex[NBUK], gbase[NBUK];
    int tid = threadIdx.x;
    // fused weight swizzle on the first 20 blocks
    int t = blockIdx.x * 256 + tid;
    if (t < 4096) wswz(W1, Wsw1, t, D_IN, D_HID);
    else if (t < 5120) wswz(W2, Wsw2, t - 4096, D_HID, D_ENC);

    if (tid < NBUK) h[tid] = 0;
    __syncthreads();
    int e0 = blockIdx.x * (256 * PB_EPT);
    unsigned int myrec[PB_EPT];
    int myb[PB_EPT];
#pragma unroll
    for (int j = 0; j < PB_EPT; ++j) {
        int e = e0 + j * 256 + tid;
        if (e < N_EDGES) {
            int s = rows[e], d = cols[e];
            myrec[j] = ((unsigned int)s << 16) | (unsigned int)d;
            myb[j] = d >> BSH;
            atomicAdd(&h[myb[j]], 1);
        } else myb[j] = -1;
    }
    __syncthreads();
    if (tid < NBUK) {
        int c = h[tid];
        gbase[tid] = tid * BCAP + (c ? atomicAdd(&bcur[tid], c) : 0);
        ex[tid] = c;
    }
    __syncthreads();
    for (int off = 1; off < NBUK; off <<= 1) {
        int v = 0;
        if (tid < NBUK && tid >= off) v = ex[tid - off];
        __syncthreads();
        if (tid < NBUK) ex[tid] += v;
        __syncthreads();
    }
    if (tid < NBUK) { ex[tid] -= h[tid]; h[tid] = 0; }
    __syncthreads();
#pragma unroll
    for (int j = 0; j < PB_EPT; ++j) {
        if (myb[j] >= 0) {
            int p = ex[myb[j]] + atomicAdd(&h[myb[j]], 1);
            recs[p] = myrec[j];
        }
    }
    __syncthreads();
    int w = tid >> 6, lane = tid & 63;
    for (int b = w; b < NBUK; b += 4) {
        int start = ex[b], cnt = h[b], gb = gbase[b];
        int lim = (b + 1) * BCAP;
        for (int i = lane; i < cnt; i += 64) {
            int gp = gb + i;
            if (gp < lim) brecs[gp] = recs[start + i];
        }
    }
}

// ---------------- per-bucket CSR: count+scan+dinv+fill, all in LDS ----------------
__global__ __launch_bounds__(512) void bucket_csr_k(const unsigned int* __restrict__ brecs,
                                                    const int* __restrict__ bcur,
                                                    int* __restrict__ rowptr,
                                                    int* __restrict__ rowcnt,
                                                    unsigned short* __restrict__ srcs,
                                                    float* __restrict__ dinv) {
    __shared__ int s[512];
    __shared__ int cur[512];
    int b = blockIdx.x;
    int cb = bcur[b]; if (cb > BCAP) cb = BCAP;
    int ebeg = b * BCAP, eend = ebeg + cb;
    int tid = threadIdx.x;
    s[tid] = 0;
    __syncthreads();
    for (int e = ebeg + tid; e < eend; e += 512)
        atomicAdd(&s[brecs[e] & BMSK], 1);
    __syncthreads();
    int v = s[tid];
    for (int off = 1; off < 512; off <<= 1) {
        int t = (tid >= off) ? s[tid - off] : 0;
        __syncthreads();
        s[tid] += t;
        __syncthreads();
    }
    int excl = s[tid] - v;
    cur[tid] = excl;
    int node = (b << BSH) + tid;
    if (node < N_NODES) {
        rowptr[node] = ebeg + excl;
        rowcnt[node] = v;
        dinv[node] = rsqrtf((float)(v + 1));   // +1 self-loop
    }
    __syncthreads();
    for (int e = ebeg + tid; e < eend; e += 512) {
        unsigned int rec = brecs[e];
        int p = atomicAdd(&cur[rec & BMSK], 1);
        srcs[ebeg + p] = (unsigned short)(rec >> 16);
    }
}

// ---------------- MFMA GEMM: H[r,:] = bf16(dinv[r] * (X[r,:] @ W)) ----------------
template<int K, int N, bool IN_BF16>
__global__ __launch_bounds__(256) void gemm_mfma_k(const void* __restrict__ Xv,
                                                   const unsigned short* __restrict__ Wsw,
                                                   const float* __restrict__ dinv,
                                                   unsigned short* __restrict__ H, int n) {
    constexpr int KS = K / 32, CT = N / 16, KP = K + 8;
    __shared__ unsigned short As[64 * KP];
    int row0 = blockIdx.x * 64;
    if (IN_BF16) {
        const ushort8v* X8 = (const ushort8v*)Xv;
        constexpr int NF8 = 64 * (K / 8);
        for (int idx = threadIdx.x; idx < NF8; idx += 256) {
            int r = idx / (K / 8), c8 = idx % (K / 8);
            int gr = row0 + r;
            ushort8v v = (gr < n) ? X8[(size_t)gr * (K / 8) + c8] : (ushort8v)0;
            *(ushort8v*)&As[r * KP + c8 * 8] = v;
        }
    } else {
        const float4* X4 = (const float4*)Xv;
        constexpr int NF4 = 64 * (K / 4);
        for (int idx = threadIdx.x; idx < NF4; idx += 256) {
            int r = idx / (K / 4), c4 = idx % (K / 4);
            int gr = row0 + r;
            float4 v = (gr < n) ? X4[(size_t)gr * (K / 4) + c4] : float4{0, 0, 0, 0};
            __hip_bfloat162 p0 = __float22bfloat162_rn(float2{v.x, v.y});   // packed RNE cvt
            __hip_bfloat162 p1 = __float22bfloat162_rn(float2{v.z, v.w});
            uint2 u; u.x = *(unsigned int*)&p0; u.y = *(unsigned int*)&p1;
            *(uint2*)&As[r * KP + c4 * 4] = u;
        }
    }
    __syncthreads();

    int w    = threadIdx.x >> 6;
    int lane = threadIdx.x & 63;
    int m    = lane & 15;
    int quad = lane >> 4;

    floatx4 acc[CT];
#pragma unroll
    for (int ct = 0; ct < CT; ++ct)
#pragma unroll
        for (int i = 0; i < 4; ++i) acc[ct][i] = 0.0f;

#pragma unroll
    for (int ks = 0; ks < KS; ++ks) {
        short8 af = *(const short8*)&As[(w * 16 + m) * KP + ks * 32 + quad * 8];
#pragma unroll
        for (int ct = 0; ct < CT; ++ct) {
            short8 bf = *(const short8*)&Wsw[(size_t)((ct * KS + ks) * 64 + lane) * 8];
            acc[ct] = __builtin_amdgcn_mfma_f32_16x16x32_bf16(af, bf, acc[ct], 0, 0, 0);
        }
    }

    int rbase = row0 + w * 16 + quad * 4;
    float dv[4];
#pragma unroll
    for (int reg = 0; reg < 4; ++reg) {
        int r = rbase + reg;
        dv[reg] = (r < n) ? dinv[r] : 0.0f;
    }
#pragma unroll
    for (int ct = 0; ct < CT; ++ct)
#pragma unroll
        for (int reg = 0; reg < 4; ++reg) {
            int r = rbase + reg;
            if (r < n) H[(size_t)r * N + ct * 16 + m] = f2bf(acc[ct][reg] * dv[reg]);
        }
}

// x8-deep gather loop: 8 independent loads in flight, 4 accumulators.
#define GATHER_LOOP(SP, STRIDE, D)                                             \
    {                                                                          \
        const auto* sp_ = (SP);                                                \
        int i = 0;                                                             \
        for (; i + 8 <= cnt; i += 8) {                                         \
            int s0 = sp_[i],     s1 = sp_[i + 1], s2 = sp_[i + 2], s3 = sp_[i + 3]; \
            int s4 = sp_[i + 4], s5 = sp_[i + 5], s6 = sp_[i + 6], s7 = sp_[i + 7]; \
            ushort8v v0 = hs[(size_t)s0 * STRIDE + D], v1 = hs[(size_t)s1 * STRIDE + D]; \
            ushort8v v2 = hs[(size_t)s2 * STRIDE + D], v3 = hs[(size_t)s3 * STRIDE + D]; \
            ushort8v v4 = hs[(size_t)s4 * STRIDE + D], v5 = hs[(size_t)s5 * STRIDE + D]; \
            ushort8v v6 = hs[(size_t)s6 * STRIDE + D], v7 = hs[(size_t)s7 * STRIDE + D]; \
            a0 += bf2f8(v0); a1 += bf2f8(v1); a2 += bf2f8(v2); a3 += bf2f8(v3); \
            a0 += bf2f8(v4); a1 += bf2f8(v5); a2 += bf2f8(v6); a3 += bf2f8(v7); \
        }                                                                      \
        if (i + 4 <= cnt) {                                                    \
            int s0 = sp_[i], s1 = sp_[i + 1], s2 = sp_[i + 2], s3 = sp_[i + 3]; \
            a0 += bf2f8(hs[(size_t)s0 * STRIDE + D]);                          \
            a1 += bf2f8(hs[(size_t)s1 * STRIDE + D]);                          \
            a2 += bf2f8(hs[(size_t)s2 * STRIDE + D]);                          \
            a3 += bf2f8(hs[(size_t)s3 * STRIDE + D]);                          \
            i += 4;                                                            \
        }                                                                      \
        for (; i < cnt; ++i)                                                   \
            a0 += bf2f8(hs[(size_t)sp_[i] * STRIDE + D]);                      \
    }

// ---------------- fused gather1 + gemm2: h2 = bf16(dinv*(relu-gathered a1 @ W2)) ----------------
// Block = 256 (4 waves), 16 nodes/block, 16 lanes/node. Block's CSR window
// (contiguous: 16-node blocks align with 512-node buckets) staged into LDS so
// index fetches are ds_read broadcasts, not global loads on the gather chain.
__global__ __launch_bounds__(256) void g1g2_k(const ushort8v* __restrict__ hs,
                                              const int* __restrict__ rowptr,
                                              const int* __restrict__ rowcnt,
                                              const unsigned short* __restrict__ srcs,
                                              const float* __restrict__ dinv,
                                              const float4* __restrict__ b1_4,
                                              const unsigned short* __restrict__ Wsw2,
                                              unsigned short* __restrict__ h2) {
    constexpr int KP = D_HID + 8;   // 136
    __shared__ unsigned short As[16 * KP];
    __shared__ unsigned short sidx[1024];   // expected ~256 (Poisson), huge margin
    __shared__ int sb2[2];
    int tid = threadIdx.x;
    int nodeb = blockIdx.x * 16;    // 50000 = 3125*16 exactly
    int ln = tid >> 4;              // local node 0..15
    int d8 = tid & 15;
    int node = nodeb + ln;
    int beg = rowptr[node];
    int cnt = rowcnt[node];
    if (tid == 0)   sb2[0] = beg;         // ln==0
    if (tid == 240) sb2[1] = beg + cnt;   // ln==15
    ushort8v selfv = hs[(size_t)node * 16 + d8];   // hoisted self-loop row
    float di = dinv[node];
    __syncthreads();
    int base = sb2[0], total = sb2[1] - base;
    for (int t = tid; t < total && t < 1024; t += 256) sidx[t] = srcs[base + t];
    __syncthreads();

    floatx8 a0 = {0,0,0,0,0,0,0,0}, a1 = a0, a2 = a0, a3 = a0;
    if (total <= 1024) {
        GATHER_LOOP(sidx + (beg - base), 16, d8)
    } else {
        GATHER_LOOP(srcs + beg, 16, d8)
    }
    floatx8 acc = a0 + a1 + a2 + a3 + bf2f8(selfv);
    float4 bA = b1_4[d8 * 2], bB = b1_4[d8 * 2 + 1];
    ushort8v r;
    r[0] = f2bf(fmaxf(di * acc[0] + bA.x, 0.0f));
    r[1] = f2bf(fmaxf(di * acc[1] + bA.y, 0.0f));
    r[2] = f2bf(fmaxf(di * acc[2] + bA.z, 0.0f));
    r[3] = f2bf(fmaxf(di * acc[3] + bA.w, 0.0f));
    r[4] = f2bf(fmaxf(di * acc[4] + bB.x, 0.0f));
    r[5] = f2bf(fmaxf(di * acc[5] + bB.y, 0.0f));
    r[6] = f2bf(fmaxf(di * acc[6] + bB.z, 0.0f));
    r[7] = f2bf(fmaxf(di * acc[7] + bB.w, 0.0f));
    *(ushort8v*)&As[ln * KP + d8 * 8] = r;
    __syncthreads();

    // phase 2: one 16-row M-tile, wave w handles col-tile w (16 cols), KS=4
    constexpr int KS = D_HID / 32;
    int w    = tid >> 6;
    int lane = tid & 63;
    int m = lane & 15, quad = lane >> 4;
    floatx4 acc2 = {0, 0, 0, 0};
#pragma unroll
    for (int ks = 0; ks < KS; ++ks) {
        short8 af = *(const short8*)&As[m * KP + ks * 32 + quad * 8];
        short8 bf = *(const short8*)&Wsw2[(size_t)((w * KS + ks) * 64 + lane) * 8];
        acc2 = __builtin_amdgcn_mfma_f32_16x16x32_bf16(af, bf, acc2, 0, 0, 0);
    }
#pragma unroll
    for (int reg = 0; reg < 4; ++reg) {
        int nn = nodeb + quad * 4 + reg;
        h2[(size_t)nn * D_ENC + w * 16 + m] = f2bf(acc2[reg] * dinv[nn]);
    }
}

// ---------------- gather layer 2 + FC + sigmoid ----------------
// 8 lanes per node (ushort8 over 64 ch), 32 concurrent nodes/block; block CSR
// window staged in LDS; x8 chains.
__global__ __launch_bounds__(256) void gather2_k(const ushort8v* __restrict__ hs, const int* __restrict__ rowptr,
                          const int* __restrict__ rowcnt, const unsigned short* __restrict__ srcs,
                          const float* __restrict__ dinv,
                          const float4* __restrict__ b4, const float4* __restrict__ Wfc4,
                          const float* __restrict__ bfc, float* __restrict__ out) {
    __shared__ unsigned short sidx[1536];   // expected ~512, huge margin
    __shared__ int sb2[2];
    int tid = threadIdx.x;
    int node = blockIdx.x * 32 + (tid >> 3);
    int d8   = tid & 7;
    bool valid = node < N_NODES;
    int cn  = valid ? node : N_NODES - 1;
    int beg = rowptr[cn];
    int rc  = rowcnt[cn];
    int cnt = valid ? rc : 0;
    if (tid == 0)   sb2[0] = beg;        // first node of block (< N_NODES always)
    if (tid == 248) sb2[1] = beg + rc;   // last node (clamped -> true global end)
    ushort8v selfv = hs[(size_t)cn * 8 + d8];
    float di = dinv[cn];
    __syncthreads();
    int base = sb2[0], total = sb2[1] - base;
    for (int t = tid; t < total && t < 1536; t += 256) sidx[t] = srcs[base + t];
    __syncthreads();

    floatx8 a0 = {0,0,0,0,0,0,0,0}, a1 = a0, a2 = a0, a3 = a0;
    if (total <= 1536) {
        GATHER_LOOP(sidx + (beg - base), 8, d8)
    } else {
        GATHER_LOOP(srcs + beg, 8, d8)
    }
    floatx8 acc = a0 + a1 + a2 + a3 + bf2f8(selfv);  // + self-loop
    float4 bA = b4[d8 * 2], bB = b4[d8 * 2 + 1];
    float4 wA = Wfc4[d8 * 2], wB = Wfc4[d8 * 2 + 1];
    float p = (di * acc[0] + bA.x) * wA.x + (di * acc[1] + bA.y) * wA.y
            + (di * acc[2] + bA.z) * wA.z + (di * acc[3] + bA.w) * wA.w
            + (di * acc[4] + bB.x) * wB.x + (di * acc[5] + bB.y) * wB.y
            + (di * acc[6] + bB.z) * wB.z + (di * acc[7] + bB.w) * wB.w;
#pragma unroll
    for (int off = 4; off; off >>= 1) p += __shfl_down(p, off, 8);
    if (valid && d8 == 0) out[node] = 1.0f / (1.0f + expf(-(p + bfc[0])));
}

extern "C" void kernel_launch(void* const* d_in, const int* in_sizes, int n_in,
                              void* d_out, int out_size, void* d_ws, size_t ws_size,
                              hipStream_t stream) {
    const float* x   = (const float*)d_in[0];
    const int*   ei  = (const int*)d_in[1];     // [2, E] int32
    const float* W1  = (const float*)d_in[2];
    const float* b1  = (const float*)d_in[3];
    const float* W2  = (const float*)d_in[4];
    const float* b2  = (const float*)d_in[5];
    const float* Wfc = (const float*)d_in[6];
    const float* bfc = (const float*)d_in[7];
    float* out = (float*)d_out;

    const int* rows = ei;             // sources
    const int* cols = ei + N_EDGES;   // targets

    // workspace layout (16B alignment kept for vector types)
    float* ws     = (float*)d_ws;
    float* dinv   = ws;                                   // 50048
    int*   rowptr = (int*)(ws + 50048);                   // 50048
    int*   rowcnt = rowptr + 50048;                       // 50048
    int*   bcur   = rowcnt + 50048;                       // 128
    unsigned int* brecs = (unsigned int*)(bcur + 128);    // NBUK*BCAP u32 (8MB)
    unsigned short* srcs = (unsigned short*)(brecs + NBUK * BCAP);  // NBUK*BCAP u16 (4MB)
    unsigned short* h1 = srcs + (size_t)NBUK * BCAP;               // 6.4M us
    unsigned short* h2 = h1 + (size_t)N_NODES * D_HID;             // 3.2M us
    unsigned short* Wsw1 = h2 + (size_t)N_NODES * D_ENC;           // 32768 us
    unsigned short* Wsw2 = Wsw1 + (size_t)D_IN * D_HID;            // 8192 us

    // ---- CSR build: fixed-capacity buckets; bcur = per-bucket counts ----
    hipMemsetAsync(bcur, 0, NBUK * sizeof(int), stream);
    part_k<<<(N_EDGES + 256 * PB_EPT - 1) / (256 * PB_EPT), 256, 0, stream>>>(
        rows, cols, bcur, brecs, W1, W2, Wsw1, Wsw2);
    bucket_csr_k<<<(N_NODES + 511) / 512, 512, 0, stream>>>(brecs, bcur, rowptr, rowcnt, srcs, dinv);

    // ---- layer 1 GEMM ----
    gemm_mfma_k<D_IN, D_HID, false><<<(N_NODES + 63) / 64, 256, 0, stream>>>(x, Wsw1, dinv, h1, N_NODES);

    // ---- fused gather1 + gemm2 ----
    g1g2_k<<<N_NODES / 16, 256, 0, stream>>>((const ushort8v*)h1, rowptr, rowcnt, srcs, dinv,
                                             (const float4*)b1, Wsw2, h2);

    // ---- gather2 + FC + sigmoid ----
    gather2_k<<<(N_NODES + 31) / 32, 256, 0, stream>>>((const ushort8v*)h2, rowptr, rowcnt, srcs, dinv,
                                                       (const float4*)b2, (const float4*)Wfc,
                                                       bfc, out);
}

// Round 3
// 190.414 us; speedup vs baseline: 1.0980x; 1.0184x over previous
//
#include <hip/hip_runtime.h>
#include <hip/hip_bf16.h>
#include <cmath>

#define N_NODES 50000
#define N_EDGES 800000
#define D_IN 256
#define D_HID 128
#define D_ENC 64
#define NBUK 128         // dest buckets, bucket = c >> 9 (98 used)
#define BSH 9
#define BMSK 511
#define BCAP 16384       // fixed bucket capacity (expected ~8.2K, huge margin)
#define PB_EPT 16        // edges per thread in part_k (4096/block)

typedef short short8 __attribute__((ext_vector_type(8)));
typedef float floatx4 __attribute__((ext_vector_type(4)));
typedef float floatx8 __attribute__((ext_vector_type(8)));
typedef unsigned short ushort8v __attribute__((ext_vector_type(8)));

static __device__ __forceinline__ unsigned short f2bf(float f) {
    unsigned int u = __float_as_uint(f);
    unsigned int r = (u + 0x7FFFu + ((u >> 16) & 1u)) >> 16;   // RNE
    return (unsigned short)r;
}
static __device__ __forceinline__ float bf2f(unsigned short u) {
    return __uint_as_float(((unsigned int)u) << 16);
}
static __device__ __forceinline__ floatx8 bf2f8(ushort8v u) {
    floatx8 f;
#pragma unroll
    for (int j = 0; j < 8; ++j) f[j] = bf2f(u[j]);
    return f;
}

// ---------------- W pre-swizzle into B-fragment layout (bf16) ----------------
static __device__ __forceinline__ void wswz(const float* __restrict__ W,
                                            unsigned short* __restrict__ Wsw,
                                            int t, int K, int N) {
    int KS = K / 32;
    int lane = t & 63;
    int ks   = (t >> 6) % KS;
    int ct   = (t >> 6) / KS;
    int m = lane & 15, quad = lane >> 4;
    int kbase = ks * 32 + quad * 8;
    int col   = ct * 16 + m;
#pragma unroll
    for (int j = 0; j < 8; ++j)
        Wsw[t * 8 + j] = f2bf(W[(size_t)(kbase + j) * N + col]);
}

// ---------------- radix partition: block-local counting sort + coalesced flush ----------------
// brecs rec = (src << 16) | dst. Bucket b occupies [b*BCAP, b*BCAP + count).
__global__ __launch_bounds__(256) void part_k(const int* __restrict__ rows,
                                              const int* __restrict__ cols,
                                              int* __restrict__ bcur,
                                              unsigned int* __restrict__ brecs,
                                              const float* __restrict__ W1,
                                              const float* __restrict__ W2,
                                              unsigned short* __restrict__ Wsw1,
                                              unsigned short* __restrict__ Wsw2) {
    __shared__ unsigned int recs[256 * PB_EPT];   // 16 KB, bucket-grouped
    __shared__ int h[NBUK], ex[NBUK], gbase[NBUK];
    int tid = threadIdx.x;
    // fused weight swizzle on the first 20 blocks
    int t = blockIdx.x * 256 + tid;
    if (t < 4096) wswz(W1, Wsw1, t, D_IN, D_HID);
    else if (t < 5120) wswz(W2, Wsw2, t - 4096, D_HID, D_ENC);

    if (tid < NBUK) h[tid] = 0;
    __syncthreads();
    int e0 = blockIdx.x * (256 * PB_EPT);
    unsigned int myrec[PB_EPT];
    int myb[PB_EPT];
#pragma unroll
    for (int j = 0; j < PB_EPT; ++j) {
        int e = e0 + j * 256 + tid;
        if (e < N_EDGES) {
            int s = rows[e], d = cols[e];
            myrec[j] = ((unsigned int)s << 16) | (unsigned int)d;
            myb[j] = d >> BSH;
            atomicAdd(&h[myb[j]], 1);
        } else myb[j] = -1;
    }
    __syncthreads();
    if (tid < NBUK) {
        int c = h[tid];
        gbase[tid] = tid * BCAP + (c ? atomicAdd(&bcur[tid], c) : 0);
        ex[tid] = c;
    }
    __syncthreads();
    for (int off = 1; off < NBUK; off <<= 1) {
        int v = 0;
        if (tid < NBUK && tid >= off) v = ex[tid - off];
        __syncthreads();
        if (tid < NBUK) ex[tid] += v;
        __syncthreads();
    }
    if (tid < NBUK) { ex[tid] -= h[tid]; h[tid] = 0; }
    __syncthreads();
#pragma unroll
    for (int j = 0; j < PB_EPT; ++j) {
        if (myb[j] >= 0) {
            int p = ex[myb[j]] + atomicAdd(&h[myb[j]], 1);
            recs[p] = myrec[j];
        }
    }
    __syncthreads();
    int w = tid >> 6, lane = tid & 63;
    for (int b = w; b < NBUK; b += 4) {
        int start = ex[b], cnt = h[b], gb = gbase[b];
        int lim = (b + 1) * BCAP;
        for (int i = lane; i < cnt; i += 64) {
            int gp = gb + i;
            if (gp < lim) brecs[gp] = recs[start + i];
        }
    }
}

// ---------------- per-bucket CSR: count+scan+dinv+fill, all in LDS ----------------
// Scatter goes into a 32 KB LDS staging buffer (random ds_write_b16 ~= free),
// then flushes to global as coalesced u32 streams — replaces 800K scattered
// 2-byte global stores (each a separate L2 RMW transaction).
__global__ __launch_bounds__(512) void bucket_csr_k(const unsigned int* __restrict__ brecs,
                                                    const int* __restrict__ bcur,
                                                    int* __restrict__ rowptr,
                                                    int* __restrict__ rowcnt,
                                                    unsigned short* __restrict__ srcs,
                                                    float* __restrict__ dinv) {
    __shared__ int s[512];
    __shared__ int cur[512];
    __shared__ unsigned short sl[BCAP];   // 32 KB in-LDS scatter staging
    int b = blockIdx.x;
    int cb = bcur[b]; if (cb > BCAP) cb = BCAP;
    int ebeg = b * BCAP, eend = ebeg + cb;
    int tid = threadIdx.x;
    s[tid] = 0;
    __syncthreads();
    for (int e = ebeg + tid; e < eend; e += 512)
        atomicAdd(&s[brecs[e] & BMSK], 1);
    __syncthreads();
    int v = s[tid];
    for (int off = 1; off < 512; off <<= 1) {
        int t = (tid >= off) ? s[tid - off] : 0;
        __syncthreads();
        s[tid] += t;
        __syncthreads();
    }
    int excl = s[tid] - v;
    cur[tid] = excl;
    int node = (b << BSH) + tid;
    if (node < N_NODES) {
        rowptr[node] = ebeg + excl;
        rowcnt[node] = v;
        dinv[node] = rsqrtf((float)(v + 1));   // +1 self-loop
    }
    __syncthreads();
    for (int e = ebeg + tid; e < eend; e += 512) {
        unsigned int rec = brecs[e];
        int p = atomicAdd(&cur[rec & BMSK], 1);
        sl[p] = (unsigned short)(rec >> 16);          // LDS scatter
    }
    __syncthreads();
    // coalesced flush: u32 pairs (BCAP even -> 4B aligned; padded tail slot
    // stays inside this bucket's private region and is never read)
    int nw = (cb + 1) >> 1;
    unsigned int* s32 = (unsigned int*)(srcs + ebeg);
    const unsigned int* l32 = (const unsigned int*)sl;
    for (int t = tid; t < nw; t += 512) s32[t] = l32[t];
}

// ---------------- MFMA GEMM: H[r,:] = bf16(dinv[r] * (X[r,:] @ W)) ----------------
template<int K, int N, bool IN_BF16>
__global__ __launch_bounds__(256) void gemm_mfma_k(const void* __restrict__ Xv,
                                                   const unsigned short* __restrict__ Wsw,
                                                   const float* __restrict__ dinv,
                                                   unsigned short* __restrict__ H, int n) {
    constexpr int KS = K / 32, CT = N / 16, KP = K + 8;
    __shared__ unsigned short As[64 * KP];
    int row0 = blockIdx.x * 64;
    if (IN_BF16) {
        const ushort8v* X8 = (const ushort8v*)Xv;
        constexpr int NF8 = 64 * (K / 8);
        for (int idx = threadIdx.x; idx < NF8; idx += 256) {
            int r = idx / (K / 8), c8 = idx % (K / 8);
            int gr = row0 + r;
            ushort8v v = (gr < n) ? X8[(size_t)gr * (K / 8) + c8] : (ushort8v)0;
            *(ushort8v*)&As[r * KP + c8 * 8] = v;
        }
    } else {
        const float4* X4 = (const float4*)Xv;
        constexpr int NF4 = 64 * (K / 4);
        for (int idx = threadIdx.x; idx < NF4; idx += 256) {
            int r = idx / (K / 4), c4 = idx % (K / 4);
            int gr = row0 + r;
            float4 v = (gr < n) ? X4[(size_t)gr * (K / 4) + c4] : float4{0, 0, 0, 0};
            __hip_bfloat162 p0 = __float22bfloat162_rn(float2{v.x, v.y});   // packed RNE cvt
            __hip_bfloat162 p1 = __float22bfloat162_rn(float2{v.z, v.w});
            uint2 u; u.x = *(unsigned int*)&p0; u.y = *(unsigned int*)&p1;
            *(uint2*)&As[r * KP + c4 * 4] = u;
        }
    }
    __syncthreads();

    int w    = threadIdx.x >> 6;
    int lane = threadIdx.x & 63;
    int m    = lane & 15;
    int quad = lane >> 4;

    floatx4 acc[CT];
#pragma unroll
    for (int ct = 0; ct < CT; ++ct)
#pragma unroll
        for (int i = 0; i < 4; ++i) acc[ct][i] = 0.0f;

#pragma unroll
    for (int ks = 0; ks < KS; ++ks) {
        short8 af = *(const short8*)&As[(w * 16 + m) * KP + ks * 32 + quad * 8];
#pragma unroll
        for (int ct = 0; ct < CT; ++ct) {
            short8 bf = *(const short8*)&Wsw[(size_t)((ct * KS + ks) * 64 + lane) * 8];
            acc[ct] = __builtin_amdgcn_mfma_f32_16x16x32_bf16(af, bf, acc[ct], 0, 0, 0);
        }
    }

    int rbase = row0 + w * 16 + quad * 4;
    float dv[4];
#pragma unroll
    for (int reg = 0; reg < 4; ++reg) {
        int r = rbase + reg;
        dv[reg] = (r < n) ? dinv[r] : 0.0f;
    }
#pragma unroll
    for (int ct = 0; ct < CT; ++ct)
#pragma unroll
        for (int reg = 0; reg < 4; ++reg) {
            int r = rbase + reg;
            if (r < n) H[(size_t)r * N + ct * 16 + m] = f2bf(acc[ct][reg] * dv[reg]);
        }
}

// x8-deep gather loop: 8 independent loads in flight, 4 accumulators.
#define GATHER_LOOP(SP, STRIDE, D)                                             \
    {                                                                          \
        const auto* sp_ = (SP);                                                \
        int i = 0;                                                             \
        for (; i + 8 <= cnt; i += 8) {                                         \
            int s0 = sp_[i],     s1 = sp_[i + 1], s2 = sp_[i + 2], s3 = sp_[i + 3]; \
            int s4 = sp_[i + 4], s5 = sp_[i + 5], s6 = sp_[i + 6], s7 = sp_[i + 7]; \
            ushort8v v0 = hs[(size_t)s0 * STRIDE + D], v1 = hs[(size_t)s1 * STRIDE + D]; \
            ushort8v v2 = hs[(size_t)s2 * STRIDE + D], v3 = hs[(size_t)s3 * STRIDE + D]; \
            ushort8v v4 = hs[(size_t)s4 * STRIDE + D], v5 = hs[(size_t)s5 * STRIDE + D]; \
            ushort8v v6 = hs[(size_t)s6 * STRIDE + D], v7 = hs[(size_t)s7 * STRIDE + D]; \
            a0 += bf2f8(v0); a1 += bf2f8(v1); a2 += bf2f8(v2); a3 += bf2f8(v3); \
            a0 += bf2f8(v4); a1 += bf2f8(v5); a2 += bf2f8(v6); a3 += bf2f8(v7); \
        }                                                                      \
        if (i + 4 <= cnt) {                                                    \
            int s0 = sp_[i], s1 = sp_[i + 1], s2 = sp_[i + 2], s3 = sp_[i + 3]; \
            a0 += bf2f8(hs[(size_t)s0 * STRIDE + D]);                          \
            a1 += bf2f8(hs[(size_t)s1 * STRIDE + D]);                          \
            a2 += bf2f8(hs[(size_t)s2 * STRIDE + D]);                          \
            a3 += bf2f8(hs[(size_t)s3 * STRIDE + D]);                          \
            i += 4;                                                            \
        }                                                                      \
        for (; i < cnt; ++i)                                                   \
            a0 += bf2f8(hs[(size_t)sp_[i] * STRIDE + D]);                      \
    }

// ---------------- fused gather1 + gemm2: h2 = bf16(dinv*(relu-gathered a1 @ W2)) ----------------
// Block = 256 (4 waves), 16 nodes/block, 16 lanes/node. Block's CSR window
// (contiguous: 16-node blocks align with 512-node buckets) staged into LDS so
// index fetches are ds_read broadcasts, not global loads on the gather chain.
__global__ __launch_bounds__(256) void g1g2_k(const ushort8v* __restrict__ hs,
                                              const int* __restrict__ rowptr,
                                              const int* __restrict__ rowcnt,
                                              const unsigned short* __restrict__ srcs,
                                              const float* __restrict__ dinv,
                                              const float4* __restrict__ b1_4,
                                              const unsigned short* __restrict__ Wsw2,
                                              unsigned short* __restrict__ h2) {
    constexpr int KP = D_HID + 8;   // 136
    __shared__ unsigned short As[16 * KP];
    __shared__ unsigned short sidx[1024];   // expected ~256 (Poisson), huge margin
    __shared__ int sb2[2];
    int tid = threadIdx.x;
    int nodeb = blockIdx.x * 16;    // 50000 = 3125*16 exactly
    int ln = tid >> 4;              // local node 0..15
    int d8 = tid & 15;
    int node = nodeb + ln;
    int beg = rowptr[node];
    int cnt = rowcnt[node];
    if (tid == 0)   sb2[0] = beg;         // ln==0
    if (tid == 240) sb2[1] = beg + cnt;   // ln==15
    ushort8v selfv = hs[(size_t)node * 16 + d8];   // hoisted self-loop row
    float di = dinv[node];
    __syncthreads();
    int base = sb2[0], total = sb2[1] - base;
    for (int t = tid; t < total && t < 1024; t += 256) sidx[t] = srcs[base + t];
    __syncthreads();

    floatx8 a0 = {0,0,0,0,0,0,0,0}, a1 = a0, a2 = a0, a3 = a0;
    if (total <= 1024) {
        GATHER_LOOP(sidx + (beg - base), 16, d8)
    } else {
        GATHER_LOOP(srcs + beg, 16, d8)
    }
    floatx8 acc = a0 + a1 + a2 + a3 + bf2f8(selfv);
    float4 bA = b1_4[d8 * 2], bB = b1_4[d8 * 2 + 1];
    ushort8v r;
    r[0] = f2bf(fmaxf(di * acc[0] + bA.x, 0.0f));
    r[1] = f2bf(fmaxf(di * acc[1] + bA.y, 0.0f));
    r[2] = f2bf(fmaxf(di * acc[2] + bA.z, 0.0f));
    r[3] = f2bf(fmaxf(di * acc[3] + bA.w, 0.0f));
    r[4] = f2bf(fmaxf(di * acc[4] + bB.x, 0.0f));
    r[5] = f2bf(fmaxf(di * acc[5] + bB.y, 0.0f));
    r[6] = f2bf(fmaxf(di * acc[6] + bB.z, 0.0f));
    r[7] = f2bf(fmaxf(di * acc[7] + bB.w, 0.0f));
    *(ushort8v*)&As[ln * KP + d8 * 8] = r;
    __syncthreads();

    // phase 2: one 16-row M-tile, wave w handles col-tile w (16 cols), KS=4
    constexpr int KS = D_HID / 32;
    int w    = tid >> 6;
    int lane = tid & 63;
    int m = lane & 15, quad = lane >> 4;
    floatx4 acc2 = {0, 0, 0, 0};
#pragma unroll
    for (int ks = 0; ks < KS; ++ks) {
        short8 af = *(const short8*)&As[m * KP + ks * 32 + quad * 8];
        short8 bf = *(const short8*)&Wsw2[(size_t)((w * KS + ks) * 64 + lane) * 8];
        acc2 = __builtin_amdgcn_mfma_f32_16x16x32_bf16(af, bf, acc2, 0, 0, 0);
    }
#pragma unroll
    for (int reg = 0; reg < 4; ++reg) {
        int nn = nodeb + quad * 4 + reg;
        h2[(size_t)nn * D_ENC + w * 16 + m] = f2bf(acc2[reg] * dinv[nn]);
    }
}

// ---------------- gather layer 2 + FC + sigmoid ----------------
// 8 lanes per node (ushort8 over 64 ch), 32 concurrent nodes/block; block CSR
// window staged in LDS; x8 chains.
__global__ __launch_bounds__(256) void gather2_k(const ushort8v* __restrict__ hs, const int* __restrict__ rowptr,
                          const int* __restrict__ rowcnt, const unsigned short* __restrict__ srcs,
                          const float* __restrict__ dinv,
                          const float4* __restrict__ b4, const float4* __restrict__ Wfc4,
                          const float* __restrict__ bfc, float* __restrict__ out) {
    __shared__ unsigned short sidx[1536];   // expected ~512, huge margin
    __shared__ int sb2[2];
    int tid = threadIdx.x;
    int node = blockIdx.x * 32 + (tid >> 3);
    int d8   = tid & 7;
    bool valid = node < N_NODES;
    int cn  = valid ? node : N_NODES - 1;
    int beg = rowptr[cn];
    int rc  = rowcnt[cn];
    int cnt = valid ? rc : 0;
    if (tid == 0)   sb2[0] = beg;        // first node of block (< N_NODES always)
    if (tid == 248) sb2[1] = beg + rc;   // last node (clamped -> true global end)
    ushort8v selfv = hs[(size_t)cn * 8 + d8];
    float di = dinv[cn];
    __syncthreads();
    int base = sb2[0], total = sb2[1] - base;
    for (int t = tid; t < total && t < 1536; t += 256) sidx[t] = srcs[base + t];
    __syncthreads();

    floatx8 a0 = {0,0,0,0,0,0,0,0}, a1 = a0, a2 = a0, a3 = a0;
    if (total <= 1536) {
        GATHER_LOOP(sidx + (beg - base), 8, d8)
    } else {
        GATHER_LOOP(srcs + beg, 8, d8)
    }
    floatx8 acc = a0 + a1 + a2 + a3 + bf2f8(selfv);  // + self-loop
    float4 bA = b4[d8 * 2], bB = b4[d8 * 2 + 1];
    float4 wA = Wfc4[d8 * 2], wB = Wfc4[d8 * 2 + 1];
    float p = (di * acc[0] + bA.x) * wA.x + (di * acc[1] + bA.y) * wA.y
            + (di * acc[2] + bA.z) * wA.z + (di * acc[3] + bA.w) * wA.w
            + (di * acc[4] + bB.x) * wB.x + (di * acc[5] + bB.y) * wB.y
            + (di * acc[6] + bB.z) * wB.z + (di * acc[7] + bB.w) * wB.w;
#pragma unroll
    for (int off = 4; off; off >>= 1) p += __shfl_down(p, off, 8);
    if (valid && d8 == 0) out[node] = 1.0f / (1.0f + expf(-(p + bfc[0])));
}

extern "C" void kernel_launch(void* const* d_in, const int* in_sizes, int n_in,
                              void* d_out, int out_size, void* d_ws, size_t ws_size,
                              hipStream_t stream) {
    const float* x   = (const float*)d_in[0];
    const int*   ei  = (const int*)d_in[1];     // [2, E] int32
    const float* W1  = (const float*)d_in[2];
    const float* b1  = (const float*)d_in[3];
    const float* W2  = (const float*)d_in[4];
    const float* b2  = (const float*)d_in[5];
    const float* Wfc = (const float*)d_in[6];
    const float* bfc = (const float*)d_in[7];
    float* out = (float*)d_out;

    const int* rows = ei;             // sources
    const int* cols = ei + N_EDGES;   // targets

    // workspace layout (16B alignment kept for vector types)
    float* ws     = (float*)d_ws;
    float* dinv   = ws;                                   // 50048
    int*   rowptr = (int*)(ws + 50048);                   // 50048
    int*   rowcnt = rowptr + 50048;                       // 50048
    int*   bcur   = rowcnt + 50048;                       // 128
    unsigned int* brecs = (unsigned int*)(bcur + 128);    // NBUK*BCAP u32 (8MB)
    unsigned short* srcs = (unsigned short*)(brecs + NBUK * BCAP);  // NBUK*BCAP u16 (4MB)
    unsigned short* h1 = srcs + (size_t)NBUK * BCAP;               // 6.4M us
    unsigned short* h2 = h1 + (size_t)N_NODES * D_HID;             // 3.2M us
    unsigned short* Wsw1 = h2 + (size_t)N_NODES * D_ENC;           // 32768 us
    unsigned short* Wsw2 = Wsw1 + (size_t)D_IN * D_HID;            // 8192 us

    // ---- CSR build: fixed-capacity buckets; bcur = per-bucket counts ----
    hipMemsetAsync(bcur, 0, NBUK * sizeof(int), stream);
    part_k<<<(N_EDGES + 256 * PB_EPT - 1) / (256 * PB_EPT), 256, 0, stream>>>(
        rows, cols, bcur, brecs, W1, W2, Wsw1, Wsw2);
    bucket_csr_k<<<(N_NODES + 511) / 512, 512, 0, stream>>>(brecs, bcur, rowptr, rowcnt, srcs, dinv);

    // ---- layer 1 GEMM ----
    gemm_mfma_k<D_IN, D_HID, false><<<(N_NODES + 63) / 64, 256, 0, stream>>>(x, Wsw1, dinv, h1, N_NODES);

    // ---- fused gather1 + gemm2 ----
    g1g2_k<<<N_NODES / 16, 256, 0, stream>>>((const ushort8v*)h1, rowptr, rowcnt, srcs, dinv,
                                             (const float4*)b1, Wsw2, h2);

    // ---- gather2 + FC + sigmoid ----
    gather2_k<<<(N_NODES + 31) / 32, 256, 0, stream>>>((const ushort8v*)h2, rowptr, rowcnt, srcs, dinv,
                                                       (const float4*)b2, (const float4*)Wfc,
                                                       bfc, out);
}

// Round 4
// 179.275 us; speedup vs baseline: 1.1663x; 1.0621x over previous
//
#include <hip/hip_runtime.h>
#include <hip/hip_bf16.h>
#include <cmath>

#define N_NODES 50000
#define N_EDGES 800000
#define D_IN 256
#define D_HID 128
#define D_ENC 64
#define NBUK 128         // dest buckets, bucket = c >> 9 (98 used)
#define BSH 9
#define BMSK 511
#define BCAP 16384       // fixed bucket capacity (expected ~8.2K, huge margin)
#define PB_EPT 16        // edges per thread in part_k (4096/block)

typedef short short8 __attribute__((ext_vector_type(8)));
typedef float floatx4 __attribute__((ext_vector_type(4)));
typedef float floatx8 __attribute__((ext_vector_type(8)));
typedef unsigned short ushort8v __attribute__((ext_vector_type(8)));

static __device__ __forceinline__ unsigned short f2bf(float f) {
    unsigned int u = __float_as_uint(f);
    unsigned int r = (u + 0x7FFFu + ((u >> 16) & 1u)) >> 16;   // RNE
    return (unsigned short)r;
}
static __device__ __forceinline__ float bf2f(unsigned short u) {
    return __uint_as_float(((unsigned int)u) << 16);
}
static __device__ __forceinline__ floatx8 bf2f8(ushort8v u) {
    floatx8 f;
#pragma unroll
    for (int j = 0; j < 8; ++j) f[j] = bf2f(u[j]);
    return f;
}

// ---------------- W pre-swizzle into B-fragment layout (bf16) ----------------
static __device__ __forceinline__ void wswz(const float* __restrict__ W,
                                            unsigned short* __restrict__ Wsw,
                                            int t, int K, int N) {
    int KS = K / 32;
    int lane = t & 63;
    int ks   = (t >> 6) % KS;
    int ct   = (t >> 6) / KS;
    int m = lane & 15, quad = lane >> 4;
    int kbase = ks * 32 + quad * 8;
    int col   = ct * 16 + m;
#pragma unroll
    for (int j = 0; j < 8; ++j)
        Wsw[t * 8 + j] = f2bf(W[(size_t)(kbase + j) * N + col]);
}

// ---------------- radix partition + weight prep ----------------
// brecs rec = (src << 16) | dst. Bucket b occupies [b*BCAP, b*BCAP + count).
// Also: Wsw1 swizzle, w2fc = W2 @ Wfc (FC folded through linear conv2), b2fc = b2 @ Wfc.
__global__ __launch_bounds__(256) void part_k(const int* __restrict__ rows,
                                              const int* __restrict__ cols,
                                              int* __restrict__ bcur,
                                              unsigned int* __restrict__ brecs,
                                              const float* __restrict__ W1,
                                              const float* __restrict__ W2,
                                              const float* __restrict__ b2,
                                              const float* __restrict__ Wfc,
                                              unsigned short* __restrict__ Wsw1,
                                              float* __restrict__ w2fc,
                                              float* __restrict__ b2fc) {
    __shared__ unsigned int recs[256 * PB_EPT];   // 16 KB, bucket-grouped
    __shared__ int h[NBUK], ex[NBUK], gbase[NBUK];
    int tid = threadIdx.x;
    int t = blockIdx.x * 256 + tid;
    if (t < 4096) wswz(W1, Wsw1, t, D_IN, D_HID);
    else if (t < 4224) {                      // w2fc[c] = sum_j W2[c][j] * Wfc[j]
        int c = t - 4096;
        float s = 0.0f;
#pragma unroll 8
        for (int j = 0; j < D_ENC; ++j) s += W2[c * D_ENC + j] * Wfc[j];
        w2fc[c] = s;
    } else if (t == 4224) {                   // b2fc = sum_j b2[j] * Wfc[j]
        float s = 0.0f;
        for (int j = 0; j < D_ENC; ++j) s += b2[j] * Wfc[j];
        b2fc[0] = s;
    }

    if (tid < NBUK) h[tid] = 0;
    __syncthreads();
    int e0 = blockIdx.x * (256 * PB_EPT);
    unsigned int myrec[PB_EPT];
    int myb[PB_EPT];
#pragma unroll
    for (int j = 0; j < PB_EPT; ++j) {
        int e = e0 + j * 256 + tid;
        if (e < N_EDGES) {
            int s = rows[e], d = cols[e];
            myrec[j] = ((unsigned int)s << 16) | (unsigned int)d;
            myb[j] = d >> BSH;
            atomicAdd(&h[myb[j]], 1);
        } else myb[j] = -1;
    }
    __syncthreads();
    if (tid < NBUK) {
        int c = h[tid];
        gbase[tid] = tid * BCAP + (c ? atomicAdd(&bcur[tid], c) : 0);
        ex[tid] = c;
    }
    __syncthreads();
    for (int off = 1; off < NBUK; off <<= 1) {
        int v = 0;
        if (tid < NBUK && tid >= off) v = ex[tid - off];
        __syncthreads();
        if (tid < NBUK) ex[tid] += v;
        __syncthreads();
    }
    if (tid < NBUK) { ex[tid] -= h[tid]; h[tid] = 0; }
    __syncthreads();
#pragma unroll
    for (int j = 0; j < PB_EPT; ++j) {
        if (myb[j] >= 0) {
            int p = ex[myb[j]] + atomicAdd(&h[myb[j]], 1);
            recs[p] = myrec[j];
        }
    }
    __syncthreads();
    int w = tid >> 6, lane = tid & 63;
    for (int b = w; b < NBUK; b += 4) {
        int start = ex[b], cnt = h[b], gb = gbase[b];
        int lim = (b + 1) * BCAP;
        for (int i = lane; i < cnt; i += 64) {
            int gp = gb + i;
            if (gp < lim) brecs[gp] = recs[start + i];
        }
    }
}

// ---------------- per-bucket CSR: count+scan+dinv+fill, all in LDS ----------------
// Scatter goes into a 32 KB LDS staging buffer, then flushes to global as
// coalesced u32 streams.
__global__ __launch_bounds__(512) void bucket_csr_k(const unsigned int* __restrict__ brecs,
                                                    const int* __restrict__ bcur,
                                                    int* __restrict__ rowptr,
                                                    int* __restrict__ rowcnt,
                                                    unsigned short* __restrict__ srcs,
                                                    float* __restrict__ dinv) {
    __shared__ int s[512];
    __shared__ int cur[512];
    __shared__ unsigned short sl[BCAP];   // 32 KB in-LDS scatter staging
    int b = blockIdx.x;
    int cb = bcur[b]; if (cb > BCAP) cb = BCAP;
    int ebeg = b * BCAP, eend = ebeg + cb;
    int tid = threadIdx.x;
    s[tid] = 0;
    __syncthreads();
    for (int e = ebeg + tid; e < eend; e += 512)
        atomicAdd(&s[brecs[e] & BMSK], 1);
    __syncthreads();
    int v = s[tid];
    for (int off = 1; off < 512; off <<= 1) {
        int t = (tid >= off) ? s[tid - off] : 0;
        __syncthreads();
        s[tid] += t;
        __syncthreads();
    }
    int excl = s[tid] - v;
    cur[tid] = excl;
    int node = (b << BSH) + tid;
    if (node < N_NODES) {
        rowptr[node] = ebeg + excl;
        rowcnt[node] = v;
        dinv[node] = rsqrtf((float)(v + 1));   // +1 self-loop
    }
    __syncthreads();
    for (int e = ebeg + tid; e < eend; e += 512) {
        unsigned int rec = brecs[e];
        int p = atomicAdd(&cur[rec & BMSK], 1);
        sl[p] = (unsigned short)(rec >> 16);          // LDS scatter
    }
    __syncthreads();
    // coalesced flush: u32 pairs (BCAP even -> 4B aligned; padded tail slot
    // stays inside this bucket's private region and is never read)
    int nw = (cb + 1) >> 1;
    unsigned int* s32 = (unsigned int*)(srcs + ebeg);
    const unsigned int* l32 = (const unsigned int*)sl;
    for (int t = tid; t < nw; t += 512) s32[t] = l32[t];
}

// ---------------- MFMA GEMM: H[r,:] = bf16(dinv[r] * (X[r,:] @ W)) ----------------
template<int K, int N, bool IN_BF16>
__global__ __launch_bounds__(256) void gemm_mfma_k(const void* __restrict__ Xv,
                                                   const unsigned short* __restrict__ Wsw,
                                                   const float* __restrict__ dinv,
                                                   unsigned short* __restrict__ H, int n) {
    constexpr int KS = K / 32, CT = N / 16, KP = K + 8;
    __shared__ unsigned short As[64 * KP];
    int row0 = blockIdx.x * 64;
    if (IN_BF16) {
        const ushort8v* X8 = (const ushort8v*)Xv;
        constexpr int NF8 = 64 * (K / 8);
        for (int idx = threadIdx.x; idx < NF8; idx += 256) {
            int r = idx / (K / 8), c8 = idx % (K / 8);
            int gr = row0 + r;
            ushort8v v = (gr < n) ? X8[(size_t)gr * (K / 8) + c8] : (ushort8v)0;
            *(ushort8v*)&As[r * KP + c8 * 8] = v;
        }
    } else {
        const float4* X4 = (const float4*)Xv;
        constexpr int NF4 = 64 * (K / 4);
        for (int idx = threadIdx.x; idx < NF4; idx += 256) {
            int r = idx / (K / 4), c4 = idx % (K / 4);
            int gr = row0 + r;
            float4 v = (gr < n) ? X4[(size_t)gr * (K / 4) + c4] : float4{0, 0, 0, 0};
            __hip_bfloat162 p0 = __float22bfloat162_rn(float2{v.x, v.y});   // packed RNE cvt
            __hip_bfloat162 p1 = __float22bfloat162_rn(float2{v.z, v.w});
            uint2 u; u.x = *(unsigned int*)&p0; u.y = *(unsigned int*)&p1;
            *(uint2*)&As[r * KP + c4 * 4] = u;
        }
    }
    __syncthreads();

    int w    = threadIdx.x >> 6;
    int lane = threadIdx.x & 63;
    int m    = lane & 15;
    int quad = lane >> 4;

    floatx4 acc[CT];
#pragma unroll
    for (int ct = 0; ct < CT; ++ct)
#pragma unroll
        for (int i = 0; i < 4; ++i) acc[ct][i] = 0.0f;

#pragma unroll
    for (int ks = 0; ks < KS; ++ks) {
        short8 af = *(const short8*)&As[(w * 16 + m) * KP + ks * 32 + quad * 8];
#pragma unroll
        for (int ct = 0; ct < CT; ++ct) {
            short8 bf = *(const short8*)&Wsw[(size_t)((ct * KS + ks) * 64 + lane) * 8];
            acc[ct] = __builtin_amdgcn_mfma_f32_16x16x32_bf16(af, bf, acc[ct], 0, 0, 0);
        }
    }

    int rbase = row0 + w * 16 + quad * 4;
    float dv[4];
#pragma unroll
    for (int reg = 0; reg < 4; ++reg) {
        int r = rbase + reg;
        dv[reg] = (r < n) ? dinv[r] : 0.0f;
    }
#pragma unroll
    for (int ct = 0; ct < CT; ++ct)
#pragma unroll
        for (int reg = 0; reg < 4; ++reg) {
            int r = rbase + reg;
            if (r < n) H[(size_t)r * N + ct * 16 + m] = f2bf(acc[ct][reg] * dv[reg]);
        }
}

// x8-deep gather loop: 8 independent loads in flight, 4 accumulators.
#define GATHER_LOOP(SP, STRIDE, D)                                             \
    {                                                                          \
        const auto* sp_ = (SP);                                                \
        int i = 0;                                                             \
        for (; i + 8 <= cnt; i += 8) {                                         \
            int s0 = sp_[i],     s1 = sp_[i + 1], s2 = sp_[i + 2], s3 = sp_[i + 3]; \
            int s4 = sp_[i + 4], s5 = sp_[i + 5], s6 = sp_[i + 6], s7 = sp_[i + 7]; \
            ushort8v v0 = hs[(size_t)s0 * STRIDE + D], v1 = hs[(size_t)s1 * STRIDE + D]; \
            ushort8v v2 = hs[(size_t)s2 * STRIDE + D], v3 = hs[(size_t)s3 * STRIDE + D]; \
            ushort8v v4 = hs[(size_t)s4 * STRIDE + D], v5 = hs[(size_t)s5 * STRIDE + D]; \
            ushort8v v6 = hs[(size_t)s6 * STRIDE + D], v7 = hs[(size_t)s7 * STRIDE + D]; \
            a0 += bf2f8(v0); a1 += bf2f8(v1); a2 += bf2f8(v2); a3 += bf2f8(v3); \
            a0 += bf2f8(v4); a1 += bf2f8(v5); a2 += bf2f8(v6); a3 += bf2f8(v7); \
        }                                                                      \
        if (i + 4 <= cnt) {                                                    \
            int s0 = sp_[i], s1 = sp_[i + 1], s2 = sp_[i + 2], s3 = sp_[i + 3]; \
            a0 += bf2f8(hs[(size_t)s0 * STRIDE + D]);                          \
            a1 += bf2f8(hs[(size_t)s1 * STRIDE + D]);                          \
            a2 += bf2f8(hs[(size_t)s2 * STRIDE + D]);                          \
            a3 += bf2f8(hs[(size_t)s3 * STRIDE + D]);                          \
            i += 4;                                                            \
        }                                                                      \
        for (; i < cnt; ++i)                                                   \
            a0 += bf2f8(hs[(size_t)sp_[i] * STRIDE + D]);                      \
    }

// ---------------- fused gather1 + relu + FC-folded projection ----------------
// z[v] = dinv[v] * ( relu(dinv[v]*gather(h1) + b1) @ w2fc )  — scalar per node.
// Block = 256 (4 waves), 16 nodes/block, 16 lanes/node; CSR window in LDS.
__global__ __launch_bounds__(256) void g1z_k(const ushort8v* __restrict__ hs,
                                             const int* __restrict__ rowptr,
                                             const int* __restrict__ rowcnt,
                                             const unsigned short* __restrict__ srcs,
                                             const float* __restrict__ dinv,
                                             const float4* __restrict__ b1_4,
                                             const float4* __restrict__ w2fc4,
                                             float* __restrict__ z) {
    __shared__ unsigned short sidx[1024];   // expected ~256 (Poisson), huge margin
    __shared__ int sb2[2];
    int tid = threadIdx.x;
    int nodeb = blockIdx.x * 16;    // 50000 = 3125*16 exactly
    int ln = tid >> 4;              // local node 0..15
    int d8 = tid & 15;
    int node = nodeb + ln;
    int beg = rowptr[node];
    int cnt = rowcnt[node];
    if (tid == 0)   sb2[0] = beg;         // ln==0
    if (tid == 240) sb2[1] = beg + cnt;   // ln==15
    ushort8v selfv = hs[(size_t)node * 16 + d8];   // hoisted self-loop row
    float di = dinv[node];
    __syncthreads();
    int base = sb2[0], total = sb2[1] - base;
    for (int t = tid; t < total && t < 1024; t += 256) sidx[t] = srcs[base + t];
    __syncthreads();

    floatx8 a0 = {0,0,0,0,0,0,0,0}, a1 = a0, a2 = a0, a3 = a0;
    if (total <= 1024) {
        GATHER_LOOP(sidx + (beg - base), 16, d8)
    } else {
        GATHER_LOOP(srcs + beg, 16, d8)
    }
    floatx8 acc = a0 + a1 + a2 + a3 + bf2f8(selfv);
    float4 bA = b1_4[d8 * 2],  bB = b1_4[d8 * 2 + 1];
    float4 wA = w2fc4[d8 * 2], wB = w2fc4[d8 * 2 + 1];
    float s = fmaxf(di * acc[0] + bA.x, 0.0f) * wA.x
            + fmaxf(di * acc[1] + bA.y, 0.0f) * wA.y
            + fmaxf(di * acc[2] + bA.z, 0.0f) * wA.z
            + fmaxf(di * acc[3] + bA.w, 0.0f) * wA.w
            + fmaxf(di * acc[4] + bB.x, 0.0f) * wB.x
            + fmaxf(di * acc[5] + bB.y, 0.0f) * wB.y
            + fmaxf(di * acc[6] + bB.z, 0.0f) * wB.z
            + fmaxf(di * acc[7] + bB.w, 0.0f) * wB.w;
#pragma unroll
    for (int off = 8; off; off >>= 1) s += __shfl_xor(s, off, 16);
    if (d8 == 0) z[node] = di * s;
}

// ---------------- scalar propagation + sigmoid ----------------
// out[v] = sigmoid( dinv[v] * (sum_{u in N(v)} z[u] + z[v]) + b2fc + bfc ).
// One thread per node; z is 200 KB (L2-resident); srcs walk is contiguous.
__global__ __launch_bounds__(256) void gatherz_k(const float* __restrict__ z,
                                                 const int* __restrict__ rowptr,
                                                 const int* __restrict__ rowcnt,
                                                 const unsigned short* __restrict__ srcs,
                                                 const float* __restrict__ dinv,
                                                 const float* __restrict__ b2fc,
                                                 const float* __restrict__ bfc,
                                                 float* __restrict__ out) {
    int v = blockIdx.x * 256 + threadIdx.x;
    if (v >= N_NODES) return;
    int beg = rowptr[v], cnt = rowcnt[v];
    float s0 = z[v], s1 = 0.0f, s2 = 0.0f, s3 = 0.0f;
    int i = beg, end = beg + cnt;
    for (; i + 4 <= end; i += 4) {
        s0 += z[srcs[i]];
        s1 += z[srcs[i + 1]];
        s2 += z[srcs[i + 2]];
        s3 += z[srcs[i + 3]];
    }
    for (; i < end; ++i) s0 += z[srcs[i]];
    float p = dinv[v] * (s0 + s1 + s2 + s3) + b2fc[0] + bfc[0];
    out[v] = 1.0f / (1.0f + expf(-p));
}

extern "C" void kernel_launch(void* const* d_in, const int* in_sizes, int n_in,
                              void* d_out, int out_size, void* d_ws, size_t ws_size,
                              hipStream_t stream) {
    const float* x   = (const float*)d_in[0];
    const int*   ei  = (const int*)d_in[1];     // [2, E] int32
    const float* W1  = (const float*)d_in[2];
    const float* b1  = (const float*)d_in[3];
    const float* W2  = (const float*)d_in[4];
    const float* b2  = (const float*)d_in[5];
    const float* Wfc = (const float*)d_in[6];
    const float* bfc = (const float*)d_in[7];
    float* out = (float*)d_out;

    const int* rows = ei;             // sources
    const int* cols = ei + N_EDGES;   // targets

    // workspace layout (16B alignment kept for vector types)
    float* ws     = (float*)d_ws;
    float* dinv   = ws;                                   // 50048 f
    int*   rowptr = (int*)(ws + 50048);                   // 50048
    int*   rowcnt = rowptr + 50048;                       // 50048
    int*   bcur   = rowcnt + 50048;                       // 128
    unsigned int* brecs = (unsigned int*)(bcur + 128);    // NBUK*BCAP u32 (8MB)
    unsigned short* srcs = (unsigned short*)(brecs + NBUK * BCAP);  // NBUK*BCAP u16 (4MB)
    unsigned short* h1 = srcs + (size_t)NBUK * BCAP;               // 6.4M us (12.8MB)
    unsigned short* Wsw1 = h1 + (size_t)N_NODES * D_HID;           // 32768 us
    float* z    = (float*)(Wsw1 + (size_t)D_IN * D_HID);           // 50000 f
    float* w2fc = z + 50000;                                       // 128 f
    float* b2fc = w2fc + 128;                                      // 1 f

    // ---- CSR build: fixed-capacity buckets; bcur = per-bucket counts ----
    hipMemsetAsync(bcur, 0, NBUK * sizeof(int), stream);
    part_k<<<(N_EDGES + 256 * PB_EPT - 1) / (256 * PB_EPT), 256, 0, stream>>>(
        rows, cols, bcur, brecs, W1, W2, b2, Wfc, Wsw1, w2fc, b2fc);
    bucket_csr_k<<<(N_NODES + 511) / 512, 512, 0, stream>>>(brecs, bcur, rowptr, rowcnt, srcs, dinv);

    // ---- layer 1 GEMM ----
    gemm_mfma_k<D_IN, D_HID, false><<<(N_NODES + 63) / 64, 256, 0, stream>>>(x, Wsw1, dinv, h1, N_NODES);

    // ---- fused gather1 + relu + (W2 @ Wfc) projection -> scalar z ----
    g1z_k<<<N_NODES / 16, 256, 0, stream>>>((const ushort8v*)h1, rowptr, rowcnt, srcs, dinv,
                                            (const float4*)b1, (const float4*)w2fc, z);

    // ---- scalar propagation + sigmoid ----
    gatherz_k<<<(N_NODES + 255) / 256, 256, 0, stream>>>(z, rowptr, rowcnt, srcs, dinv,
                                                         b2fc, bfc, out);
}

// Round 5
// 164.940 us; speedup vs baseline: 1.2676x; 1.0869x over previous
//
#include <hip/hip_runtime.h>
#include <hip/hip_bf16.h>
#include <cmath>

#define N_NODES 50000
#define N_EDGES 800000
#define D_IN 256
#define D_HID 128
#define D_ENC 64
#define NBUK 128         // dest buckets, bucket = c >> 9 (98 used)
#define BSH 9
#define BMSK 511
#define BCAP 16384       // fixed bucket capacity (expected ~8.2K, huge margin)
#define PB_EPT 16        // edges per thread in part_k (4096/block)
#define NCSRB 98         // ceil(N_NODES/512) CSR bucket-blocks
#define NGEMB 782        // ceil(N_NODES/64) GEMM tile-blocks

typedef short short8 __attribute__((ext_vector_type(8)));
typedef float floatx4 __attribute__((ext_vector_type(4)));
typedef float floatx8 __attribute__((ext_vector_type(8)));
typedef unsigned short ushort8v __attribute__((ext_vector_type(8)));

static __device__ __forceinline__ unsigned short f2bf(float f) {
    unsigned int u = __float_as_uint(f);
    unsigned int r = (u + 0x7FFFu + ((u >> 16) & 1u)) >> 16;   // RNE
    return (unsigned short)r;
}
static __device__ __forceinline__ float bf2f(unsigned short u) {
    return __uint_as_float(((unsigned int)u) << 16);
}
static __device__ __forceinline__ floatx8 bf2f8(ushort8v u) {
    floatx8 f;
#pragma unroll
    for (int j = 0; j < 8; ++j) f[j] = bf2f(u[j]);
    return f;
}

// ---------------- W pre-swizzle into B-fragment layout (bf16) ----------------
static __device__ __forceinline__ void wswz(const float* __restrict__ W,
                                            unsigned short* __restrict__ Wsw,
                                            int t, int K, int N) {
    int KS = K / 32;
    int lane = t & 63;
    int ks   = (t >> 6) % KS;
    int ct   = (t >> 6) / KS;
    int m = lane & 15, quad = lane >> 4;
    int kbase = ks * 32 + quad * 8;
    int col   = ct * 16 + m;
#pragma unroll
    for (int j = 0; j < 8; ++j)
        Wsw[t * 8 + j] = f2bf(W[(size_t)(kbase + j) * N + col]);
}

// ---------------- radix partition + weight prep ----------------
// brecs rec = (src << 16) | dst. Bucket b occupies [b*BCAP, b*BCAP + count).
// Also: Wsw1 swizzle, w2fc = W2 @ Wfc (FC folded through linear conv2), b2fc = b2 @ Wfc.
__global__ __launch_bounds__(256) void part_k(const int* __restrict__ rows,
                                              const int* __restrict__ cols,
                                              int* __restrict__ bcur,
                                              unsigned int* __restrict__ brecs,
                                              const float* __restrict__ W1,
                                              const float* __restrict__ W2,
                                              const float* __restrict__ b2,
                                              const float* __restrict__ Wfc,
                                              unsigned short* __restrict__ Wsw1,
                                              float* __restrict__ w2fc,
                                              float* __restrict__ b2fc) {
    __shared__ unsigned int recs[256 * PB_EPT];   // 16 KB, bucket-grouped
    __shared__ int h[NBUK], ex[NBUK], gbase[NBUK];
    int tid = threadIdx.x;
    int t = blockIdx.x * 256 + tid;
    if (t < 4096) wswz(W1, Wsw1, t, D_IN, D_HID);
    else if (t < 4224) {                      // w2fc[c] = sum_j W2[c][j] * Wfc[j]
        int c = t - 4096;
        float s = 0.0f;
#pragma unroll 8
        for (int j = 0; j < D_ENC; ++j) s += W2[c * D_ENC + j] * Wfc[j];
        w2fc[c] = s;
    } else if (t == 4224) {                   // b2fc = sum_j b2[j] * Wfc[j]
        float s = 0.0f;
        for (int j = 0; j < D_ENC; ++j) s += b2[j] * Wfc[j];
        b2fc[0] = s;
    }

    if (tid < NBUK) h[tid] = 0;
    __syncthreads();
    int e0 = blockIdx.x * (256 * PB_EPT);
    unsigned int myrec[PB_EPT];
    int myb[PB_EPT];
#pragma unroll
    for (int j = 0; j < PB_EPT; ++j) {
        int e = e0 + j * 256 + tid;
        if (e < N_EDGES) {
            int s = rows[e], d = cols[e];
            myrec[j] = ((unsigned int)s << 16) | (unsigned int)d;
            myb[j] = d >> BSH;
            atomicAdd(&h[myb[j]], 1);
        } else myb[j] = -1;
    }
    __syncthreads();
    if (tid < NBUK) {
        int c = h[tid];
        gbase[tid] = tid * BCAP + (c ? atomicAdd(&bcur[tid], c) : 0);
        ex[tid] = c;
    }
    __syncthreads();
    for (int off = 1; off < NBUK; off <<= 1) {
        int v = 0;
        if (tid < NBUK && tid >= off) v = ex[tid - off];
        __syncthreads();
        if (tid < NBUK) ex[tid] += v;
        __syncthreads();
    }
    if (tid < NBUK) { ex[tid] -= h[tid]; h[tid] = 0; }
    __syncthreads();
#pragma unroll
    for (int j = 0; j < PB_EPT; ++j) {
        if (myb[j] >= 0) {
            int p = ex[myb[j]] + atomicAdd(&h[myb[j]], 1);
            recs[p] = myrec[j];
        }
    }
    __syncthreads();
    int w = tid >> 6, lane = tid & 63;
    for (int b = w; b < NBUK; b += 4) {
        int start = ex[b], cnt = h[b], gb = gbase[b];
        int lim = (b + 1) * BCAP;
        for (int i = lane; i < cnt; i += 64) {
            int gp = gb + i;
            if (gp < lim) brecs[gp] = recs[start + i];
        }
    }
}

// ---------------- fused CSR-build + layer-1 GEMM (independent work, one dispatch) ----------------
// Blocks 0..NCSRB-1: per-bucket CSR (count+scan+dinv+LDS-staged scatter+coalesced flush).
// Blocks NCSRB..NCSRB+NGEMB-1: MFMA GEMM tile, H[r,:] = bf16((X[r,:] @ W1)) — dinv
// normalization deferred to g1z (removes the CSR->GEMM dependency so both overlap).
// Dynamic LDS union: CSR 36864 B, GEMM 64*(D_IN+8)*2 = 33792 B.
__global__ __launch_bounds__(512) void csr_gemm_k(const unsigned int* __restrict__ brecs,
                                                  const int* __restrict__ bcur,
                                                  int* __restrict__ rowptr,
                                                  int* __restrict__ rowcnt,
                                                  unsigned short* __restrict__ srcs,
                                                  float* __restrict__ dinv,
                                                  const float4* __restrict__ X4,
                                                  const unsigned short* __restrict__ Wsw,
                                                  unsigned short* __restrict__ H) {
    extern __shared__ char dynsm[];
    int tid = threadIdx.x;
    if (blockIdx.x < NCSRB) {
        // ---- CSR path (512 threads) ----
        int* s   = (int*)dynsm;                       // 512 ints
        int* cur = (int*)(dynsm + 2048);              // 512 ints
        unsigned short* sl = (unsigned short*)(dynsm + 4096);   // BCAP u16 (32 KB)
        int b = blockIdx.x;
        int cb = bcur[b]; if (cb > BCAP) cb = BCAP;
        int ebeg = b * BCAP, eend = ebeg + cb;
        s[tid] = 0;
        __syncthreads();
        for (int e = ebeg + tid; e < eend; e += 512)
            atomicAdd(&s[brecs[e] & BMSK], 1);
        __syncthreads();
        int v = s[tid];
        for (int off = 1; off < 512; off <<= 1) {
            int t = (tid >= off) ? s[tid - off] : 0;
            __syncthreads();
            s[tid] += t;
            __syncthreads();
        }
        int excl = s[tid] - v;
        cur[tid] = excl;
        int node = (b << BSH) + tid;
        if (node < N_NODES) {
            rowptr[node] = ebeg + excl;
            rowcnt[node] = v;
            dinv[node] = rsqrtf((float)(v + 1));   // +1 self-loop
        }
        __syncthreads();
        for (int e = ebeg + tid; e < eend; e += 512) {
            unsigned int rec = brecs[e];
            int p = atomicAdd(&cur[rec & BMSK], 1);
            sl[p] = (unsigned short)(rec >> 16);          // LDS scatter
        }
        __syncthreads();
        int nw = (cb + 1) >> 1;
        unsigned int* s32 = (unsigned int*)(srcs + ebeg);
        const unsigned int* l32 = (const unsigned int*)sl;
        for (int t = tid; t < nw; t += 512) s32[t] = l32[t];
    } else {
        // ---- GEMM path (512 threads = 8 waves; 64-row tile; wave w: row-sub w&3, ct-half w>>2) ----
        constexpr int KP = D_IN + 8;   // 264
        unsigned short* As = (unsigned short*)dynsm;    // 64*KP u16
        int row0 = (blockIdx.x - NCSRB) * 64;
        for (int idx = tid; idx < 64 * 64; idx += 512) {
            int r = idx >> 6, c4 = idx & 63;
            int gr = row0 + r;
            float4 v = (gr < N_NODES) ? X4[(size_t)gr * 64 + c4] : float4{0, 0, 0, 0};
            __hip_bfloat162 p0 = __float22bfloat162_rn(float2{v.x, v.y});   // packed RNE cvt
            __hip_bfloat162 p1 = __float22bfloat162_rn(float2{v.z, v.w});
            uint2 u; u.x = *(unsigned int*)&p0; u.y = *(unsigned int*)&p1;
            *(uint2*)&As[r * KP + c4 * 4] = u;
        }
        __syncthreads();

        int w    = tid >> 6;
        int lane = tid & 63;
        int m    = lane & 15;
        int quad = lane >> 4;
        int rsub = w & 3;
        int cth  = w >> 2;              // 0/1: which 4 col-tiles

        floatx4 acc[4];
#pragma unroll
        for (int ct = 0; ct < 4; ++ct)
#pragma unroll
            for (int i = 0; i < 4; ++i) acc[ct][i] = 0.0f;

#pragma unroll
        for (int ks = 0; ks < D_IN / 32; ++ks) {
            short8 af = *(const short8*)&As[(rsub * 16 + m) * KP + ks * 32 + quad * 8];
#pragma unroll
            for (int ct = 0; ct < 4; ++ct) {
                int ct4 = cth * 4 + ct;
                short8 bf = *(const short8*)&Wsw[(size_t)((ct4 * (D_IN / 32) + ks) * 64 + lane) * 8];
                acc[ct] = __builtin_amdgcn_mfma_f32_16x16x32_bf16(af, bf, acc[ct], 0, 0, 0);
            }
        }

        int rbase = row0 + rsub * 16 + quad * 4;
#pragma unroll
        for (int ct = 0; ct < 4; ++ct) {
            int col = (cth * 4 + ct) * 16 + m;
#pragma unroll
            for (int reg = 0; reg < 4; ++reg) {
                int r = rbase + reg;
                if (r < N_NODES) H[(size_t)r * D_HID + col] = f2bf(acc[ct][reg]);
            }
        }
    }
}

// x8-deep WEIGHTED gather: acc += dinv[s] * h1raw[s]; 8 loads in flight.
#define WGATHER(SP)                                                            \
    {                                                                          \
        const auto* sp_ = (SP);                                                \
        int i = 0;                                                             \
        for (; i + 8 <= cnt; i += 8) {                                         \
            int s0 = sp_[i],     s1 = sp_[i + 1], s2 = sp_[i + 2], s3 = sp_[i + 3]; \
            int s4 = sp_[i + 4], s5 = sp_[i + 5], s6 = sp_[i + 6], s7 = sp_[i + 7]; \
            float w0 = dinv[s0], w1 = dinv[s1], w2 = dinv[s2], w3 = dinv[s3];  \
            float w4 = dinv[s4], w5 = dinv[s5], w6 = dinv[s6], w7 = dinv[s7];  \
            ushort8v v0 = hs[(size_t)s0 * 16 + d8], v1 = hs[(size_t)s1 * 16 + d8]; \
            ushort8v v2 = hs[(size_t)s2 * 16 + d8], v3 = hs[(size_t)s3 * 16 + d8]; \
            ushort8v v4 = hs[(size_t)s4 * 16 + d8], v5 = hs[(size_t)s5 * 16 + d8]; \
            ushort8v v6 = hs[(size_t)s6 * 16 + d8], v7 = hs[(size_t)s7 * 16 + d8]; \
            a0 += bf2f8(v0) * w0; a1 += bf2f8(v1) * w1;                        \
            a2 += bf2f8(v2) * w2; a3 += bf2f8(v3) * w3;                        \
            a0 += bf2f8(v4) * w4; a1 += bf2f8(v5) * w5;                        \
            a2 += bf2f8(v6) * w6; a3 += bf2f8(v7) * w7;                        \
        }                                                                      \
        if (i + 4 <= cnt) {                                                    \
            int s0 = sp_[i], s1 = sp_[i + 1], s2 = sp_[i + 2], s3 = sp_[i + 3]; \
            a0 += bf2f8(hs[(size_t)s0 * 16 + d8]) * dinv[s0];                  \
            a1 += bf2f8(hs[(size_t)s1 * 16 + d8]) * dinv[s1];                  \
            a2 += bf2f8(hs[(size_t)s2 * 16 + d8]) * dinv[s2];                  \
            a3 += bf2f8(hs[(size_t)s3 * 16 + d8]) * dinv[s3];                  \
            i += 4;                                                            \
        }                                                                      \
        for (; i < cnt; ++i) {                                                 \
            int s = sp_[i];                                                    \
            a0 += bf2f8(hs[(size_t)s * 16 + d8]) * dinv[s];                    \
        }                                                                      \
    }

// ---------------- fused gather1 + relu + FC-folded projection ----------------
// z[v] = dinv[v] * ( relu(dinv[v]*Σ dinv[s]*h1raw[s] + b1) @ w2fc )  — scalar per node.
// Block = 256 (4 waves), 16 nodes/block, 16 lanes/node; CSR window in LDS.
__global__ __launch_bounds__(256) void g1z_k(const ushort8v* __restrict__ hs,
                                             const int* __restrict__ rowptr,
                                             const int* __restrict__ rowcnt,
                                             const unsigned short* __restrict__ srcs,
                                             const float* __restrict__ dinv,
                                             const float4* __restrict__ b1_4,
                                             const float4* __restrict__ w2fc4,
                                             float* __restrict__ z) {
    __shared__ unsigned short sidx[1024];   // expected ~256 (Poisson), huge margin
    __shared__ int sb2[2];
    int tid = threadIdx.x;
    int nodeb = blockIdx.x * 16;    // 50000 = 3125*16 exactly
    int ln = tid >> 4;              // local node 0..15
    int d8 = tid & 15;
    int node = nodeb + ln;
    int beg = rowptr[node];
    int cnt = rowcnt[node];
    if (tid == 0)   sb2[0] = beg;         // ln==0
    if (tid == 240) sb2[1] = beg + cnt;   // ln==15
    ushort8v selfv = hs[(size_t)node * 16 + d8];   // hoisted self-loop row
    float di = dinv[node];
    __syncthreads();
    int base = sb2[0], total = sb2[1] - base;
    for (int t = tid; t < total && t < 1024; t += 256) sidx[t] = srcs[base + t];
    __syncthreads();

    floatx8 a0 = {0,0,0,0,0,0,0,0}, a1 = a0, a2 = a0, a3 = a0;
    if (total <= 1024) {
        WGATHER(sidx + (beg - base))
    } else {
        WGATHER(srcs + beg)
    }
    floatx8 acc = a0 + a1 + a2 + a3 + bf2f8(selfv) * di;
    float4 bA = b1_4[d8 * 2],  bB = b1_4[d8 * 2 + 1];
    float4 wA = w2fc4[d8 * 2], wB = w2fc4[d8 * 2 + 1];
    float s = fmaxf(di * acc[0] + bA.x, 0.0f) * wA.x
            + fmaxf(di * acc[1] + bA.y, 0.0f) * wA.y
            + fmaxf(di * acc[2] + bA.z, 0.0f) * wA.z
            + fmaxf(di * acc[3] + bA.w, 0.0f) * wA.w
            + fmaxf(di * acc[4] + bB.x, 0.0f) * wB.x
            + fmaxf(di * acc[5] + bB.y, 0.0f) * wB.y
            + fmaxf(di * acc[6] + bB.z, 0.0f) * wB.z
            + fmaxf(di * acc[7] + bB.w, 0.0f) * wB.w;
#pragma unroll
    for (int off = 8; off; off >>= 1) s += __shfl_xor(s, off, 16);
    if (d8 == 0) z[node] = di * s;
}

// ---------------- scalar propagation + sigmoid ----------------
// out[v] = sigmoid( dinv[v] * (sum_{u in N(v)} z[u] + z[v]) + b2fc + bfc ).
// One thread per node; z is 200 KB (L2-resident); srcs walk is contiguous.
__global__ __launch_bounds__(256) void gatherz_k(const float* __restrict__ z,
                                                 const int* __restrict__ rowptr,
                                                 const int* __restrict__ rowcnt,
                                                 const unsigned short* __restrict__ srcs,
                                                 const float* __restrict__ dinv,
                                                 const float* __restrict__ b2fc,
                                                 const float* __restrict__ bfc,
                                                 float* __restrict__ out) {
    int v = blockIdx.x * 256 + threadIdx.x;
    if (v >= N_NODES) return;
    int beg = rowptr[v], cnt = rowcnt[v];
    float s0 = z[v], s1 = 0.0f, s2 = 0.0f, s3 = 0.0f;
    int i = beg, end = beg + cnt;
    for (; i + 4 <= end; i += 4) {
        s0 += z[srcs[i]];
        s1 += z[srcs[i + 1]];
        s2 += z[srcs[i + 2]];
        s3 += z[srcs[i + 3]];
    }
    for (; i < end; ++i) s0 += z[srcs[i]];
    float p = dinv[v] * (s0 + s1 + s2 + s3) + b2fc[0] + bfc[0];
    out[v] = 1.0f / (1.0f + expf(-p));
}

extern "C" void kernel_launch(void* const* d_in, const int* in_sizes, int n_in,
                              void* d_out, int out_size, void* d_ws, size_t ws_size,
                              hipStream_t stream) {
    const float* x   = (const float*)d_in[0];
    const int*   ei  = (const int*)d_in[1];     // [2, E] int32
    const float* W1  = (const float*)d_in[2];
    const float* b1  = (const float*)d_in[3];
    const float* W2  = (const float*)d_in[4];
    const float* b2  = (const float*)d_in[5];
    const float* Wfc = (const float*)d_in[6];
    const float* bfc = (const float*)d_in[7];
    float* out = (float*)d_out;

    const int* rows = ei;             // sources
    const int* cols = ei + N_EDGES;   // targets

    // workspace layout (16B alignment kept for vector types)
    float* ws     = (float*)d_ws;
    float* dinv   = ws;                                   // 50048 f
    int*   rowptr = (int*)(ws + 50048);                   // 50048
    int*   rowcnt = rowptr + 50048;                       // 50048
    int*   bcur   = rowcnt + 50048;                       // 128
    unsigned int* brecs = (unsigned int*)(bcur + 128);    // NBUK*BCAP u32 (8MB)
    unsigned short* srcs = (unsigned short*)(brecs + NBUK * BCAP);  // NBUK*BCAP u16 (4MB)
    unsigned short* h1 = srcs + (size_t)NBUK * BCAP;               // 6.4M us (12.8MB)
    unsigned short* Wsw1 = h1 + (size_t)N_NODES * D_HID;           // 32768 us
    float* z    = (float*)(Wsw1 + (size_t)D_IN * D_HID);           // 50000 f
    float* w2fc = z + 50000;                                       // 128 f
    float* b2fc = w2fc + 128;                                      // 1 f

    // ---- CSR build: fixed-capacity buckets; bcur = per-bucket counts ----
    hipMemsetAsync(bcur, 0, NBUK * sizeof(int), stream);
    part_k<<<(N_EDGES + 256 * PB_EPT - 1) / (256 * PB_EPT), 256, 0, stream>>>(
        rows, cols, bcur, brecs, W1, W2, b2, Wfc, Wsw1, w2fc, b2fc);

    // ---- fused: per-bucket CSR finalize (98 blocks) || layer-1 GEMM (782 blocks) ----
    csr_gemm_k<<<NCSRB + NGEMB, 512, 36864, stream>>>(brecs, bcur, rowptr, rowcnt, srcs, dinv,
                                                      (const float4*)x, Wsw1, h1);

    // ---- fused gather1 (dinv-weighted) + relu + (W2 @ Wfc) projection -> scalar z ----
    g1z_k<<<N_NODES / 16, 256, 0, stream>>>((const ushort8v*)h1, rowptr, rowcnt, srcs, dinv,
                                            (const float4*)b1, (const float4*)w2fc, z);

    // ---- scalar propagation + sigmoid ----
    gatherz_k<<<(N_NODES + 255) / 256, 256, 0, stream>>>(z, rowptr, rowcnt, srcs, dinv,
                                                         b2fc, bfc, out);
}

// Round 6
// 161.173 us; speedup vs baseline: 1.2973x; 1.0234x over previous
//
#include <hip/hip_runtime.h>
#include <hip/hip_bf16.h>
#include <cmath>

#define N_NODES 50000
#define N_EDGES 800000
#define D_IN 256
#define D_HID 128
#define D_ENC 64
#define NBUK 128         // dest buckets, bucket = c >> 9 (98 used)
#define BSH 9
#define BMSK 511
#define BCAP 16384       // fixed bucket capacity (expected ~8.2K, huge margin)
#define PBF_EPT 8        // edges per thread in fused part path (4096/block @ 512 thr)
#define NPARTB 196       // ceil(N_EDGES/4096)
#define NGEMB 782        // ceil(N_NODES/64) GEMM tile-blocks

typedef short short8 __attribute__((ext_vector_type(8)));
typedef float floatx4 __attribute__((ext_vector_type(4)));
typedef float floatx8 __attribute__((ext_vector_type(8)));
typedef unsigned short ushort8v __attribute__((ext_vector_type(8)));

static __device__ __forceinline__ unsigned short f2bf(float f) {
    unsigned int u = __float_as_uint(f);
    unsigned int r = (u + 0x7FFFu + ((u >> 16) & 1u)) >> 16;   // RNE
    return (unsigned short)r;
}
static __device__ __forceinline__ float bf2f(unsigned short u) {
    return __uint_as_float(((unsigned int)u) << 16);
}
static __device__ __forceinline__ floatx8 bf2f8(ushort8v u) {
    floatx8 f;
#pragma unroll
    for (int j = 0; j < 8; ++j) f[j] = bf2f(u[j]);
    return f;
}

// ---------------- W pre-swizzle into B-fragment layout (bf16) ----------------
static __device__ __forceinline__ void wswz(const float* __restrict__ W,
                                            unsigned short* __restrict__ Wsw,
                                            int t, int K, int N) {
    int KS = K / 32;
    int lane = t & 63;
    int ks   = (t >> 6) % KS;
    int ct   = (t >> 6) / KS;
    int m = lane & 15, quad = lane >> 4;
    int kbase = ks * 32 + quad * 8;
    int col   = ct * 16 + m;
#pragma unroll
    for (int j = 0; j < 8; ++j)
        Wsw[t * 8 + j] = f2bf(W[(size_t)(kbase + j) * N + col]);
}

// ---------------- k0: weight prep + bcur zero (frees GEMM from part dependency) ----------------
__global__ __launch_bounds__(256) void prep_k(const float* __restrict__ W1,
                                              const float* __restrict__ W2,
                                              const float* __restrict__ b2,
                                              const float* __restrict__ Wfc,
                                              unsigned short* __restrict__ Wsw1,
                                              float* __restrict__ w2fc,
                                              float* __restrict__ b2fc,
                                              int* __restrict__ bcur) {
    int t = blockIdx.x * 256 + threadIdx.x;
    if (t < 4096) wswz(W1, Wsw1, t, D_IN, D_HID);
    else if (t < 4224) {                      // w2fc[c] = sum_j W2[c][j] * Wfc[j]
        int c = t - 4096;
        float s = 0.0f;
#pragma unroll 8
        for (int j = 0; j < D_ENC; ++j) s += W2[c * D_ENC + j] * Wfc[j];
        w2fc[c] = s;
    } else if (t == 4224) {                   // b2fc = sum_j b2[j] * Wfc[j]
        float s = 0.0f;
        for (int j = 0; j < D_ENC; ++j) s += b2[j] * Wfc[j];
        b2fc[0] = s;
    } else if (t >= 4225 && t < 4225 + NBUK) {
        bcur[t - 4225] = 0;
    }
}

// ---------------- fused radix partition || layer-1 GEMM (independent, one dispatch) ----------------
// Blocks 0..NPARTB-1: block-local counting sort of 4096 edges -> bucket-grouped
//   coalesced flush into brecs (rec = (src<<16)|dst; bucket b at [b*BCAP, +count)).
// Blocks NPARTB.. : MFMA GEMM tile, H[r,:] = bf16(X[r,:] @ W1), dinv deferred to g1z.
// Dynamic LDS union: part 17920 B, GEMM 64*(D_IN+8)*2 = 33792 B -> 36864.
__global__ __launch_bounds__(512) void partgemm_k(const int* __restrict__ rows,
                                                  const int* __restrict__ cols,
                                                  int* __restrict__ bcur,
                                                  unsigned int* __restrict__ brecs,
                                                  const float4* __restrict__ X4,
                                                  const unsigned short* __restrict__ Wsw,
                                                  unsigned short* __restrict__ H) {
    extern __shared__ char dynsm[];
    int tid = threadIdx.x;
    if (blockIdx.x < NPARTB) {
        // ---- partition path (512 threads, 4096 edges/block) ----
        unsigned int* recs = (unsigned int*)dynsm;        // 4096 u32 (16 KB)
        int* h     = (int*)(dynsm + 16384);               // NBUK
        int* ex    = h + NBUK;                            // NBUK
        int* gbase = ex + NBUK;                           // NBUK
        if (tid < NBUK) h[tid] = 0;
        __syncthreads();
        int e0 = blockIdx.x * 4096;
        unsigned int myrec[PBF_EPT];
        int myb[PBF_EPT];
#pragma unroll
        for (int j = 0; j < PBF_EPT; ++j) {
            int e = e0 + j * 512 + tid;
            if (e < N_EDGES) {
                int s = rows[e], d = cols[e];
                myrec[j] = ((unsigned int)s << 16) | (unsigned int)d;
                myb[j] = d >> BSH;
                atomicAdd(&h[myb[j]], 1);
            } else myb[j] = -1;
        }
        __syncthreads();
        if (tid < NBUK) {
            int c = h[tid];
            gbase[tid] = tid * BCAP + (c ? atomicAdd(&bcur[tid], c) : 0);
            ex[tid] = c;
        }
        __syncthreads();
        for (int off = 1; off < NBUK; off <<= 1) {
            int v = 0;
            if (tid < NBUK && tid >= off) v = ex[tid - off];
            __syncthreads();
            if (tid < NBUK) ex[tid] += v;
            __syncthreads();
        }
        if (tid < NBUK) { ex[tid] -= h[tid]; h[tid] = 0; }
        __syncthreads();
#pragma unroll
        for (int j = 0; j < PBF_EPT; ++j) {
            if (myb[j] >= 0) {
                int p = ex[myb[j]] + atomicAdd(&h[myb[j]], 1);
                recs[p] = myrec[j];
            }
        }
        __syncthreads();
        int w = tid >> 6, lane = tid & 63;
        for (int b = w; b < NBUK; b += 8) {
            int start = ex[b], cnt = h[b], gb = gbase[b];
            int lim = (b + 1) * BCAP;
            for (int i = lane; i < cnt; i += 64) {
                int gp = gb + i;
                if (gp < lim) brecs[gp] = recs[start + i];
            }
        }
    } else {
        // ---- GEMM path (8 waves; 64-row tile; wave w: row-sub w&3, ct-half w>>2) ----
        constexpr int KP = D_IN + 8;   // 264
        unsigned short* As = (unsigned short*)dynsm;    // 64*KP u16
        int row0 = (blockIdx.x - NPARTB) * 64;
        for (int idx = tid; idx < 64 * 64; idx += 512) {
            int r = idx >> 6, c4 = idx & 63;
            int gr = row0 + r;
            float4 v = (gr < N_NODES) ? X4[(size_t)gr * 64 + c4] : float4{0, 0, 0, 0};
            __hip_bfloat162 p0 = __float22bfloat162_rn(float2{v.x, v.y});   // packed RNE cvt
            __hip_bfloat162 p1 = __float22bfloat162_rn(float2{v.z, v.w});
            uint2 u; u.x = *(unsigned int*)&p0; u.y = *(unsigned int*)&p1;
            *(uint2*)&As[r * KP + c4 * 4] = u;
        }
        __syncthreads();

        int w    = tid >> 6;
        int lane = tid & 63;
        int m    = lane & 15;
        int quad = lane >> 4;
        int rsub = w & 3;
        int cth  = w >> 2;              // 0/1: which 4 col-tiles

        floatx4 acc[4];
#pragma unroll
        for (int ct = 0; ct < 4; ++ct)
#pragma unroll
            for (int i = 0; i < 4; ++i) acc[ct][i] = 0.0f;

#pragma unroll
        for (int ks = 0; ks < D_IN / 32; ++ks) {
            short8 af = *(const short8*)&As[(rsub * 16 + m) * KP + ks * 32 + quad * 8];
#pragma unroll
            for (int ct = 0; ct < 4; ++ct) {
                int ct4 = cth * 4 + ct;
                short8 bf = *(const short8*)&Wsw[(size_t)((ct4 * (D_IN / 32) + ks) * 64 + lane) * 8];
                acc[ct] = __builtin_amdgcn_mfma_f32_16x16x32_bf16(af, bf, acc[ct], 0, 0, 0);
            }
        }

        int rbase = row0 + rsub * 16 + quad * 4;
#pragma unroll
        for (int ct = 0; ct < 4; ++ct) {
            int col = (cth * 4 + ct) * 16 + m;
#pragma unroll
            for (int reg = 0; reg < 4; ++reg) {
                int r = rbase + reg;
                if (r < N_NODES) H[(size_t)r * D_HID + col] = f2bf(acc[ct][reg]);
            }
        }
    }
}

// ---------------- per-bucket CSR: count+scan+dinv+fill, all in LDS ----------------
__global__ __launch_bounds__(512) void bucket_csr_k(const unsigned int* __restrict__ brecs,
                                                    const int* __restrict__ bcur,
                                                    int* __restrict__ rowptr,
                                                    int* __restrict__ rowcnt,
                                                    unsigned short* __restrict__ srcs,
                                                    float* __restrict__ dinv) {
    __shared__ int s[512];
    __shared__ int cur[512];
    __shared__ unsigned short sl[BCAP];   // 32 KB in-LDS scatter staging
    int b = blockIdx.x;
    int cb = bcur[b]; if (cb > BCAP) cb = BCAP;
    int ebeg = b * BCAP, eend = ebeg + cb;
    int tid = threadIdx.x;
    s[tid] = 0;
    __syncthreads();
    for (int e = ebeg + tid; e < eend; e += 512)
        atomicAdd(&s[brecs[e] & BMSK], 1);
    __syncthreads();
    int v = s[tid];
    for (int off = 1; off < 512; off <<= 1) {
        int t = (tid >= off) ? s[tid - off] : 0;
        __syncthreads();
        s[tid] += t;
        __syncthreads();
    }
    int excl = s[tid] - v;
    cur[tid] = excl;
    int node = (b << BSH) + tid;
    if (node < N_NODES) {
        rowptr[node] = ebeg + excl;
        rowcnt[node] = v;
        dinv[node] = rsqrtf((float)(v + 1));   // +1 self-loop
    }
    __syncthreads();
    for (int e = ebeg + tid; e < eend; e += 512) {
        unsigned int rec = brecs[e];
        int p = atomicAdd(&cur[rec & BMSK], 1);
        sl[p] = (unsigned short)(rec >> 16);          // LDS scatter
    }
    __syncthreads();
    // coalesced flush: u32 pairs (BCAP even -> 4B aligned; padded tail slot
    // stays inside this bucket's private region and is never read)
    int nw = (cb + 1) >> 1;
    unsigned int* s32 = (unsigned int*)(srcs + ebeg);
    const unsigned int* l32 = (const unsigned int*)sl;
    for (int t = tid; t < nw; t += 512) s32[t] = l32[t];
}

// x8-deep WEIGHTED gather: acc += dinv[s] * h1raw[s]; 8 loads in flight.
#define WGATHER(SP)                                                            \
    {                                                                          \
        const auto* sp_ = (SP);                                                \
        int i = 0;                                                             \
        for (; i + 8 <= cnt; i += 8) {                                         \
            int s0 = sp_[i],     s1 = sp_[i + 1], s2 = sp_[i + 2], s3 = sp_[i + 3]; \
            int s4 = sp_[i + 4], s5 = sp_[i + 5], s6 = sp_[i + 6], s7 = sp_[i + 7]; \
            float w0 = dinv[s0], w1 = dinv[s1], w2 = dinv[s2], w3 = dinv[s3];  \
            float w4 = dinv[s4], w5 = dinv[s5], w6 = dinv[s6], w7 = dinv[s7];  \
            ushort8v v0 = hs[(size_t)s0 * 16 + d8], v1 = hs[(size_t)s1 * 16 + d8]; \
            ushort8v v2 = hs[(size_t)s2 * 16 + d8], v3 = hs[(size_t)s3 * 16 + d8]; \
            ushort8v v4 = hs[(size_t)s4 * 16 + d8], v5 = hs[(size_t)s5 * 16 + d8]; \
            ushort8v v6 = hs[(size_t)s6 * 16 + d8], v7 = hs[(size_t)s7 * 16 + d8]; \
            a0 += bf2f8(v0) * w0; a1 += bf2f8(v1) * w1;                        \
            a2 += bf2f8(v2) * w2; a3 += bf2f8(v3) * w3;                        \
            a0 += bf2f8(v4) * w4; a1 += bf2f8(v5) * w5;                        \
            a2 += bf2f8(v6) * w6; a3 += bf2f8(v7) * w7;                        \
        }                                                                      \
        if (i + 4 <= cnt) {                                                    \
            int s0 = sp_[i], s1 = sp_[i + 1], s2 = sp_[i + 2], s3 = sp_[i + 3]; \
            a0 += bf2f8(hs[(size_t)s0 * 16 + d8]) * dinv[s0];                  \
            a1 += bf2f8(hs[(size_t)s1 * 16 + d8]) * dinv[s1];                  \
            a2 += bf2f8(hs[(size_t)s2 * 16 + d8]) * dinv[s2];                  \
            a3 += bf2f8(hs[(size_t)s3 * 16 + d8]) * dinv[s3];                  \
            i += 4;                                                            \
        }                                                                      \
        for (; i < cnt; ++i) {                                                 \
            int s = sp_[i];                                                    \
            a0 += bf2f8(hs[(size_t)s * 16 + d8]) * dinv[s];                    \
        }                                                                      \
    }

// ---------------- fused gather1 + relu + FC-folded projection ----------------
// z[v] = dinv[v] * ( relu(dinv[v]*Σ dinv[s]*h1raw[s] + b1) @ w2fc )  — scalar per node.
// Block = 256 (4 waves), 16 nodes/block, 16 lanes/node; CSR window in LDS.
__global__ __launch_bounds__(256) void g1z_k(const ushort8v* __restrict__ hs,
                                             const int* __restrict__ rowptr,
                                             const int* __restrict__ rowcnt,
                                             const unsigned short* __restrict__ srcs,
                                             const float* __restrict__ dinv,
                                             const float4* __restrict__ b1_4,
                                             const float4* __restrict__ w2fc4,
                                             float* __restrict__ z) {
    __shared__ unsigned short sidx[1024];   // expected ~256 (Poisson), huge margin
    __shared__ int sb2[2];
    int tid = threadIdx.x;
    int nodeb = blockIdx.x * 16;    // 50000 = 3125*16 exactly
    int ln = tid >> 4;              // local node 0..15
    int d8 = tid & 15;
    int node = nodeb + ln;
    int beg = rowptr[node];
    int cnt = rowcnt[node];
    if (tid == 0)   sb2[0] = beg;         // ln==0
    if (tid == 240) sb2[1] = beg + cnt;   // ln==15
    ushort8v selfv = hs[(size_t)node * 16 + d8];   // hoisted self-loop row
    float di = dinv[node];
    __syncthreads();
    int base = sb2[0], total = sb2[1] - base;
    for (int t = tid; t < total && t < 1024; t += 256) sidx[t] = srcs[base + t];
    __syncthreads();

    floatx8 a0 = {0,0,0,0,0,0,0,0}, a1 = a0, a2 = a0, a3 = a0;
    if (total <= 1024) {
        WGATHER(sidx + (beg - base))
    } else {
        WGATHER(srcs + beg)
    }
    floatx8 acc = a0 + a1 + a2 + a3 + bf2f8(selfv) * di;
    float4 bA = b1_4[d8 * 2],  bB = b1_4[d8 * 2 + 1];
    float4 wA = w2fc4[d8 * 2], wB = w2fc4[d8 * 2 + 1];
    float s = fmaxf(di * acc[0] + bA.x, 0.0f) * wA.x
            + fmaxf(di * acc[1] + bA.y, 0.0f) * wA.y
            + fmaxf(di * acc[2] + bA.z, 0.0f) * wA.z
            + fmaxf(di * acc[3] + bA.w, 0.0f) * wA.w
            + fmaxf(di * acc[4] + bB.x, 0.0f) * wB.x
            + fmaxf(di * acc[5] + bB.y, 0.0f) * wB.y
            + fmaxf(di * acc[6] + bB.z, 0.0f) * wB.z
            + fmaxf(di * acc[7] + bB.w, 0.0f) * wB.w;
#pragma unroll
    for (int off = 8; off; off >>= 1) s += __shfl_xor(s, off, 16);
    if (d8 == 0) z[node] = di * s;
}

// ---------------- scalar propagation + sigmoid ----------------
// out[v] = sigmoid( dinv[v] * (sum_{u in N(v)} z[u] + z[v]) + b2fc + bfc ).
// One thread per node; z is 200 KB (L2-resident); srcs walk is contiguous.
__global__ __launch_bounds__(256) void gatherz_k(const float* __restrict__ z,
                                                 const int* __restrict__ rowptr,
                                                 const int* __restrict__ rowcnt,
                                                 const unsigned short* __restrict__ srcs,
                                                 const float* __restrict__ dinv,
                                                 const float* __restrict__ b2fc,
                                                 const float* __restrict__ bfc,
                                                 float* __restrict__ out) {
    int v = blockIdx.x * 256 + threadIdx.x;
    if (v >= N_NODES) return;
    int beg = rowptr[v], cnt = rowcnt[v];
    float s0 = z[v], s1 = 0.0f, s2 = 0.0f, s3 = 0.0f;
    int i = beg, end = beg + cnt;
    for (; i + 4 <= end; i += 4) {
        s0 += z[srcs[i]];
        s1 += z[srcs[i + 1]];
        s2 += z[srcs[i + 2]];
        s3 += z[srcs[i + 3]];
    }
    for (; i < end; ++i) s0 += z[srcs[i]];
    float p = dinv[v] * (s0 + s1 + s2 + s3) + b2fc[0] + bfc[0];
    out[v] = 1.0f / (1.0f + expf(-p));
}

extern "C" void kernel_launch(void* const* d_in, const int* in_sizes, int n_in,
                              void* d_out, int out_size, void* d_ws, size_t ws_size,
                              hipStream_t stream) {
    const float* x   = (const float*)d_in[0];
    const int*   ei  = (const int*)d_in[1];     // [2, E] int32
    const float* W1  = (const float*)d_in[2];
    const float* b1  = (const float*)d_in[3];
    const float* W2  = (const float*)d_in[4];
    const float* b2  = (const float*)d_in[5];
    const float* Wfc = (const float*)d_in[6];
    const float* bfc = (const float*)d_in[7];
    float* out = (float*)d_out;

    const int* rows = ei;             // sources
    const int* cols = ei + N_EDGES;   // targets

    // workspace layout (16B alignment kept for vector types)
    float* ws     = (float*)d_ws;
    float* dinv   = ws;                                   // 50048 f
    int*   rowptr = (int*)(ws + 50048);                   // 50048
    int*   rowcnt = rowptr + 50048;                       // 50048
    int*   bcur   = rowcnt + 50048;                       // 128
    unsigned int* brecs = (unsigned int*)(bcur + 128);    // NBUK*BCAP u32 (8MB)
    unsigned short* srcs = (unsigned short*)(brecs + NBUK * BCAP);  // NBUK*BCAP u16 (4MB)
    unsigned short* h1 = srcs + (size_t)NBUK * BCAP;               // 6.4M us (12.8MB)
    unsigned short* Wsw1 = h1 + (size_t)N_NODES * D_HID;           // 32768 us
    float* z    = (float*)(Wsw1 + (size_t)D_IN * D_HID);           // 50000 f
    float* w2fc = z + 50000;                                       // 128 f
    float* b2fc = w2fc + 128;                                      // 1 f

    // ---- k0: weight swizzle + FC fold + bcur zero (GEMM no longer waits on part) ----
    prep_k<<<18, 256, 0, stream>>>(W1, W2, b2, Wfc, Wsw1, w2fc, b2fc, bcur);

    // ---- fused: radix partition (196 blocks) || layer-1 GEMM (782 blocks) ----
    partgemm_k<<<NPARTB + NGEMB, 512, 36864, stream>>>(rows, cols, bcur, brecs,
                                                       (const float4*)x, Wsw1, h1);

    // ---- per-bucket CSR finalize ----
    bucket_csr_k<<<(N_NODES + 511) / 512, 512, 0, stream>>>(brecs, bcur, rowptr, rowcnt, srcs, dinv);

    // ---- fused gather1 (dinv-weighted) + relu + (W2 @ Wfc) projection -> scalar z ----
    g1z_k<<<N_NODES / 16, 256, 0, stream>>>((const ushort8v*)h1, rowptr, rowcnt, srcs, dinv,
                                            (const float4*)b1, (const float4*)w2fc, z);

    // ---- scalar propagation + sigmoid ----
    gatherz_k<<<(N_NODES + 255) / 256, 256, 0, stream>>>(z, rowptr, rowcnt, srcs, dinv,
                                                         b2fc, bfc, out);
}